// Round 1
// 306.038 us; speedup vs baseline: 1.0852x; 1.0852x over previous
//
#include <hip/hip_runtime.h>
#include <hip/hip_bf16.h>
#include <cstdio>

#define NB 2
#define NN 4096
#define NC 64
#define NQ 16
#define POS_COEF 0.1f

// ---- workspace layout (float offsets) ----
#define OFF_QT   0u            // [B][N][16] row-major q
#define OFF_QK   131072u       // [B][16][N] planar k-major q (coalesced stream)
#define OFF_XYZ4 262144u       // [B][N][4]  row-major xyz+sq
#define OFF_XYZK 294912u       // [B][4][N]  planar xyz+sq
#define OFF_IRS1 327680u       // [B][N]
#define OFF_IRS2 335872u       // [B][N]
#define OFF_THR  344064u       // [B][N]
#define OFF_ICS1 352256u       // [B][N]  1/(1e-9+cs1)
#define OFF_FLAG 360448u       // [16]
#define OFF_XVB  360464u       // [B][64][N] bf16 (262144 floats)
// --- zeroed region below ---
#define OFF_SUMS 622608u       // [B][4]
#define OFF_GN   622616u       // [2][B][8]
#define OFF_CS2  622648u       // [B][N] colsum of local
#define OFF_GMA  630840u       // [B][N][64]  G1 -> res in k8
#define OFF_G2   1155128u      // [B][N][64]  G2 (unnormalized local part)
#define WS_TOTAL 1679416u
#define ZERO_F   (WS_TOTAL - OFF_SUMS)
// --- optional materialized exp matrices (bf16), used iff ws_size permits ---
#define OFF_A0   1679424u      // [B][N][N] bf16 exp(corr)     (16777216 floats)
#define OFF_AE   18456640u     // [B][N][N] bf16 exp(l0)       (16777216 floats)
#define FULL_F   35233856u

using bf16x8 = __attribute__((ext_vector_type(8))) short;
using f32x4v = __attribute__((ext_vector_type(4))) float;

__device__ __forceinline__ float rcpf_(float x) { return __builtin_amdgcn_rcpf(x); }
__device__ __forceinline__ unsigned short f2bf(float x) {
  __hip_bfloat16 h = __float2bfloat16(x);
  return *(unsigned short*)&h;
}
__device__ __forceinline__ float bf2f(unsigned short u) {
  unsigned v = ((unsigned)u) << 16;
  return __builtin_bit_cast(float, v);
}

__device__ __forceinline__ float ldin(const void* p, size_t i, bool f32) {
  return f32 ? ((const float*)p)[i]
             : __bfloat162float(((const __hip_bfloat16*)p)[i]);
}

// 16-term fma tree, named float4 row against named float4 row
#define DOT16M(A0,A1,A2,A3,B0,B1,B2,B3) \
  fmaf((A0).x,(B0).x, fmaf((A0).y,(B0).y, fmaf((A0).z,(B0).z, fmaf((A0).w,(B0).w, \
  fmaf((A1).x,(B1).x, fmaf((A1).y,(B1).y, fmaf((A1).z,(B1).z, fmaf((A1).w,(B1).w, \
  fmaf((A2).x,(B2).x, fmaf((A2).y,(B2).y, fmaf((A2).z,(B2).z, fmaf((A2).w,(B2).w, \
  fmaf((A3).x,(B3).x, fmaf((A3).y,(B3).y, fmaf((A3).z,(B3).z, (A3).w*(B3).w)))))))))))))))

// dot of named row (M0..M3) against column C of k-planes k0..k15
#define DOTC(M0,M1,M2,M3,C) \
  fmaf((M0).x,k0.C, fmaf((M0).y,k1.C, fmaf((M0).z,k2.C, fmaf((M0).w,k3.C, \
  fmaf((M1).x,k4.C, fmaf((M1).y,k5.C, fmaf((M1).z,k6.C, fmaf((M1).w,k7.C, \
  fmaf((M2).x,k8.C, fmaf((M2).y,k9.C, fmaf((M2).z,k10.C, fmaf((M2).w,k11.C, \
  fmaf((M3).x,k12.C, fmaf((M3).y,k13.C, fmaf((M3).z,k14.C, (M3).w*k15.C)))))))))))))))

// planar k-plane loads: lanes read consecutive float4 -> fully coalesced
#define LKPL(base, n0) \
  const float4 k0  = *(const float4*)((base) + 0*NN  + (n0)); \
  const float4 k1  = *(const float4*)((base) + 1*NN  + (n0)); \
  const float4 k2  = *(const float4*)((base) + 2*NN  + (n0)); \
  const float4 k3  = *(const float4*)((base) + 3*NN  + (n0)); \
  const float4 k4  = *(const float4*)((base) + 4*NN  + (n0)); \
  const float4 k5  = *(const float4*)((base) + 5*NN  + (n0)); \
  const float4 k6  = *(const float4*)((base) + 6*NN  + (n0)); \
  const float4 k7  = *(const float4*)((base) + 7*NN  + (n0)); \
  const float4 k8  = *(const float4*)((base) + 8*NN  + (n0)); \
  const float4 k9  = *(const float4*)((base) + 9*NN  + (n0)); \
  const float4 k10 = *(const float4*)((base) + 10*NN + (n0)); \
  const float4 k11 = *(const float4*)((base) + 11*NN + (n0)); \
  const float4 k12 = *(const float4*)((base) + 12*NN + (n0)); \
  const float4 k13 = *(const float4*)((base) + 13*NN + (n0)); \
  const float4 k14 = *(const float4*)((base) + 14*NN + (n0)); \
  const float4 k15 = *(const float4*)((base) + 15*NN + (n0));

#define WRED(s) { s += __shfl_xor(s, 32); s += __shfl_xor(s, 16); \
  s += __shfl_xor(s, 8); s += __shfl_xor(s, 4); s += __shfl_xor(s, 2); s += __shfl_xor(s, 1); }

#define LQROW(v, base) \
  const float4 v##0 = *(const float4*)((base)); \
  const float4 v##1 = *(const float4*)((base) + 4); \
  const float4 v##2 = *(const float4*)((base) + 8); \
  const float4 v##3 = *(const float4*)((base) + 12);

// K0: detect input dtype
__global__ __launch_bounds__(256) void k0_detect(
    const unsigned short* __restrict__ ctx_u16, float* __restrict__ flag) {
  const int tid = threadIdx.x;
  int bad = 0;
  for (int i = tid; i < 8192; i += 256) {
    const unsigned short u = ctx_u16[i];
    const int e = (u >> 7) & 0xFF;
    if (e >= 134 || (e >= 1 && e <= 100)) bad++;
  }
  __shared__ int cnt;
  if (tid == 0) cnt = 0;
  __syncthreads();
  atomicAdd(&cnt, bad);
  __syncthreads();
  if (tid == 0) flag[0] = (cnt > 256) ? 1.0f : 0.0f;
}

// K1: q = Wqk @ ctx (row-major + planar), xyz (row + planar), batch sums
__global__ __launch_bounds__(256) void k1_q_xyz(
    const void* __restrict__ ctx, const void* __restrict__ xyz,
    const void* __restrict__ wqk, const float* __restrict__ flag,
    float* __restrict__ qt, float* __restrict__ qk,
    float* __restrict__ xyz4, float* __restrict__ xyzk,
    float* __restrict__ sums) {
  const bool f32 = flag[0] > 0.5f;
  const int tid = threadIdx.x;
  const int b = blockIdx.x >> 4;
  const int n = ((blockIdx.x & 15) << 8) + tid;
  __shared__ float wqT[NQ * NC];  // [c][o]
  for (int i = tid; i < NQ * NC; i += 256) {
    int o = i & 15, c = i >> 4;
    wqT[c * 16 + o] = ldin(wqk, o * 64 + c, f32);
  }
  __syncthreads();
  float4 a0 = {0,0,0,0}, a1 = {0,0,0,0}, a2 = {0,0,0,0}, a3 = {0,0,0,0};
  const size_t cbase = (size_t)b * 64 * NN + n;
#pragma unroll 4
  for (int c = 0; c < 64; ++c) {
    float x = ldin(ctx, cbase + (size_t)c * NN, f32);
    const float4 w0 = *(const float4*)(wqT + c * 16 + 0);
    const float4 w1 = *(const float4*)(wqT + c * 16 + 4);
    const float4 w2 = *(const float4*)(wqT + c * 16 + 8);
    const float4 w3 = *(const float4*)(wqT + c * 16 + 12);
    a0.x = fmaf(w0.x, x, a0.x); a0.y = fmaf(w0.y, x, a0.y); a0.z = fmaf(w0.z, x, a0.z); a0.w = fmaf(w0.w, x, a0.w);
    a1.x = fmaf(w1.x, x, a1.x); a1.y = fmaf(w1.y, x, a1.y); a1.z = fmaf(w1.z, x, a1.z); a1.w = fmaf(w1.w, x, a1.w);
    a2.x = fmaf(w2.x, x, a2.x); a2.y = fmaf(w2.y, x, a2.y); a2.z = fmaf(w2.z, x, a2.z); a2.w = fmaf(w2.w, x, a2.w);
    a3.x = fmaf(w3.x, x, a3.x); a3.y = fmaf(w3.y, x, a3.y); a3.z = fmaf(w3.z, x, a3.z); a3.w = fmaf(w3.w, x, a3.w);
  }
  float* qp = qt + (size_t)(b * NN + n) * 16;
  *(float4*)(qp + 0) = a0; *(float4*)(qp + 4) = a1;
  *(float4*)(qp + 8) = a2; *(float4*)(qp + 12) = a3;
  float* kq = qk + (size_t)b * 16 * NN + n;
  kq[0*NN]=a0.x;  kq[1*NN]=a0.y;  kq[2*NN]=a0.z;  kq[3*NN]=a0.w;
  kq[4*NN]=a1.x;  kq[5*NN]=a1.y;  kq[6*NN]=a1.z;  kq[7*NN]=a1.w;
  kq[8*NN]=a2.x;  kq[9*NN]=a2.y;  kq[10*NN]=a2.z; kq[11*NN]=a2.w;
  kq[12*NN]=a3.x; kq[13*NN]=a3.y; kq[14*NN]=a3.z; kq[15*NN]=a3.w;
  float xx = ldin(xyz, (size_t)(b * NN + n) * 3 + 0, f32);
  float yy = ldin(xyz, (size_t)(b * NN + n) * 3 + 1, f32);
  float zz = ldin(xyz, (size_t)(b * NN + n) * 3 + 2, f32);
  float4 p; p.x = xx; p.y = yy; p.z = zz; p.w = fmaf(xx, xx, fmaf(yy, yy, zz * zz));
  *(float4*)(xyz4 + (size_t)(b * NN + n) * 4) = p;
  float* kx = xyzk + (size_t)b * 4 * NN + n;
  kx[0*NN]=p.x; kx[1*NN]=p.y; kx[2*NN]=p.z; kx[3*NN]=p.w;
  float sx = p.x, sy = p.y, sz = p.z, sw = p.w;
  WRED(sx) WRED(sy) WRED(sz) WRED(sw)
  if ((tid & 63) == 0) {
    atomicAdd(&sums[b * 4 + 0], sx);
    atomicAdd(&sums[b * 4 + 1], sy);
    atomicAdd(&sums[b * 4 + 2], sz);
    atomicAdd(&sums[b * 4 + 3], sw);
  }
}

// K2: xv = Wv @ motion + bv, bf16 channel-major [b][c][n]
__global__ __launch_bounds__(256) void k2_xv(
    const void* __restrict__ mot, const void* __restrict__ wv,
    const void* __restrict__ bv, const float* __restrict__ flag,
    unsigned short* __restrict__ xvb) {
  const bool f32 = flag[0] > 0.5f;
  const int tid = threadIdx.x;
  const int b = blockIdx.x >> 6;
  const int n = ((blockIdx.x & 63) << 6) + (tid >> 2);
  const int og = tid & 3;
  __shared__ float wvT[NC * NC];
  __shared__ float bvs[NC];
  for (int i = tid; i < NC * NC; i += 256) {
    int o = i & 63, c = i >> 6;
    wvT[c * 64 + o] = ldin(wv, o * 64 + c, f32);
  }
  if (tid < 64) bvs[tid] = ldin(bv, tid, f32);
  __syncthreads();
  float4 a0 = *(const float4*)(bvs + og * 16 + 0);
  float4 a1 = *(const float4*)(bvs + og * 16 + 4);
  float4 a2 = *(const float4*)(bvs + og * 16 + 8);
  float4 a3 = *(const float4*)(bvs + og * 16 + 12);
  const size_t mbase = (size_t)b * 64 * NN + n;
#pragma unroll 4
  for (int c = 0; c < 64; ++c) {
    float x = ldin(mot, mbase + (size_t)c * NN, f32);
    const float4 w0 = *(const float4*)(wvT + c * 64 + og * 16 + 0);
    const float4 w1 = *(const float4*)(wvT + c * 64 + og * 16 + 4);
    const float4 w2 = *(const float4*)(wvT + c * 64 + og * 16 + 8);
    const float4 w3 = *(const float4*)(wvT + c * 64 + og * 16 + 12);
    a0.x = fmaf(w0.x, x, a0.x); a0.y = fmaf(w0.y, x, a0.y); a0.z = fmaf(w0.z, x, a0.z); a0.w = fmaf(w0.w, x, a0.w);
    a1.x = fmaf(w1.x, x, a1.x); a1.y = fmaf(w1.y, x, a1.y); a1.z = fmaf(w1.z, x, a1.z); a1.w = fmaf(w1.w, x, a1.w);
    a2.x = fmaf(w2.x, x, a2.x); a2.y = fmaf(w2.y, x, a2.y); a2.z = fmaf(w2.z, x, a2.z); a2.w = fmaf(w2.w, x, a2.w);
    a3.x = fmaf(w3.x, x, a3.x); a3.y = fmaf(w3.y, x, a3.y); a3.z = fmaf(w3.z, x, a3.z); a3.w = fmaf(w3.w, x, a3.w);
  }
  unsigned short* xb = xvb + (size_t)b * 64 * NN + n;
  const int o0 = og * 16;
  xb[(size_t)(o0 + 0) * NN] = f2bf(a0.x);  xb[(size_t)(o0 + 1) * NN] = f2bf(a0.y);
  xb[(size_t)(o0 + 2) * NN] = f2bf(a0.z);  xb[(size_t)(o0 + 3) * NN] = f2bf(a0.w);
  xb[(size_t)(o0 + 4) * NN] = f2bf(a1.x);  xb[(size_t)(o0 + 5) * NN] = f2bf(a1.y);
  xb[(size_t)(o0 + 6) * NN] = f2bf(a1.z);  xb[(size_t)(o0 + 7) * NN] = f2bf(a1.w);
  xb[(size_t)(o0 + 8) * NN] = f2bf(a2.x);  xb[(size_t)(o0 + 9) * NN] = f2bf(a2.y);
  xb[(size_t)(o0 +10) * NN] = f2bf(a2.z);  xb[(size_t)(o0 +11) * NN] = f2bf(a2.w);
  xb[(size_t)(o0 +12) * NN] = f2bf(a3.x);  xb[(size_t)(o0 +13) * NN] = f2bf(a3.y);
  xb[(size_t)(o0 +14) * NN] = f2bf(a3.z);  xb[(size_t)(o0 +15) * NN] = f2bf(a3.w);
}

// K2b: thr[n] = 0.1*(1e-9 + csd[n]) analytic
__global__ __launch_bounds__(256) void k2b_thr(
    const float* __restrict__ xyz4, const float* __restrict__ sums,
    float* __restrict__ thr) {
  const int idx = blockIdx.x * 256 + threadIdx.x;
  const int b = idx >> 12;
  const float4 pn = *(const float4*)(xyz4 + (size_t)idx * 4);
  const float Px = sums[b * 4 + 0], Py = sums[b * 4 + 1];
  const float Pz = sums[b * 4 + 2], S1 = sums[b * 4 + 3];
  float csd = fmaf((float)NN, pn.w, S1)
            - 2.f * (pn.x * Px + pn.y * Py + pn.z * Pz);
  thr[idx] = POS_COEF * (1e-9f + csd);
}

// ===================== fallback (round-13) p1/p3/k7 =====================

__global__ __launch_bounds__(256) void p1_rs1(
    const float* __restrict__ qt, const float* __restrict__ qk,
    float* __restrict__ irs1) {
  const int tid = threadIdx.x;
  const int b = blockIdx.x >> 8;
  const int m0 = (blockIdx.x & 255) << 4;
  const int w = tid >> 6, lane = tid & 63;
  const float* qb = qt + (size_t)b * NN * 16;
  const float* kb = qk + (size_t)b * 16 * NN;
  const int mA = m0 + w, mB = m0 + w + 4, mC = m0 + w + 8, mD = m0 + w + 12;
  LQROW(ma, qb + (size_t)mA * 16)
  LQROW(mb, qb + (size_t)mB * 16)
  LQROW(mc, qb + (size_t)mC * 16)
  LQROW(md, qb + (size_t)mD * 16)
  float sA = 0.f, sB = 0.f, sC = 0.f, sD = 0.f;
  for (int it = 0; it < 16; ++it) {
    const int n0 = (it << 8) + (lane << 2);
    LKPL(kb, n0)
    sA += __expf(fminf(DOTC(ma0,ma1,ma2,ma3,x), 80.f));
    sA += __expf(fminf(DOTC(ma0,ma1,ma2,ma3,y), 80.f));
    sA += __expf(fminf(DOTC(ma0,ma1,ma2,ma3,z), 80.f));
    sA += __expf(fminf(DOTC(ma0,ma1,ma2,ma3,w), 80.f));
    sB += __expf(fminf(DOTC(mb0,mb1,mb2,mb3,x), 80.f));
    sB += __expf(fminf(DOTC(mb0,mb1,mb2,mb3,y), 80.f));
    sB += __expf(fminf(DOTC(mb0,mb1,mb2,mb3,z), 80.f));
    sB += __expf(fminf(DOTC(mb0,mb1,mb2,mb3,w), 80.f));
    sC += __expf(fminf(DOTC(mc0,mc1,mc2,mc3,x), 80.f));
    sC += __expf(fminf(DOTC(mc0,mc1,mc2,mc3,y), 80.f));
    sC += __expf(fminf(DOTC(mc0,mc1,mc2,mc3,z), 80.f));
    sC += __expf(fminf(DOTC(mc0,mc1,mc2,mc3,w), 80.f));
    sD += __expf(fminf(DOTC(md0,md1,md2,md3,x), 80.f));
    sD += __expf(fminf(DOTC(md0,md1,md2,md3,y), 80.f));
    sD += __expf(fminf(DOTC(md0,md1,md2,md3,z), 80.f));
    sD += __expf(fminf(DOTC(md0,md1,md2,md3,w), 80.f));
  }
  WRED(sA) WRED(sB) WRED(sC) WRED(sD)
  if (lane == 0) {
    irs1[b * NN + mA] = rcpf_(sA);
    irs1[b * NN + mB] = rcpf_(sB);
    irs1[b * NN + mC] = rcpf_(sC);
    irs1[b * NN + mD] = rcpf_(sD);
  }
}

__global__ __launch_bounds__(256) void p3_rs2(
    const float* __restrict__ qt, const float* __restrict__ qk,
    const float* __restrict__ xyz4, const float* __restrict__ xyzk,
    const float* __restrict__ irs1, const float* __restrict__ ics1,
    const float* __restrict__ thr, float* __restrict__ irs2) {
  const int tid = threadIdx.x;
  const int b = blockIdx.x >> 8;
  const int m0 = (blockIdx.x & 255) << 4;
  const int w = tid >> 6, lane = tid & 63;
  const float* qb = qt + (size_t)b * NN * 16;
  const float* kb = qk + (size_t)b * 16 * NN;
  const float* xk = xyzk + (size_t)b * 4 * NN;
  const int mA = m0 + w, mB = m0 + w + 4, mC = m0 + w + 8, mD = m0 + w + 12;
  LQROW(ma, qb + (size_t)mA * 16)
  LQROW(mb, qb + (size_t)mB * 16)
  LQROW(mc, qb + (size_t)mC * 16)
  LQROW(md, qb + (size_t)mD * 16)
  const float4 pmA = *(const float4*)(xyz4 + ((size_t)b * NN + mA) * 4);
  const float4 pmB = *(const float4*)(xyz4 + ((size_t)b * NN + mB) * 4);
  const float4 pmC = *(const float4*)(xyz4 + ((size_t)b * NN + mC) * 4);
  const float4 pmD = *(const float4*)(xyz4 + ((size_t)b * NN + mD) * 4);
  const float rA = irs1[b * NN + mA];
  const float rB = irs1[b * NN + mB];
  const float rC = irs1[b * NN + mC];
  const float rD = irs1[b * NN + mD];
  float sA = 0.f, sB = 0.f, sC = 0.f, sD = 0.f;
#define P3C(S, M0,M1,M2,M3, PM, R, C) { \
    float corr_ = DOTC(M0,M1,M2,M3,C); \
    float a1v_ = __expf(fminf(corr_, 80.f)) * (R) * ic.C; \
    float dd_ = (PM).w + pw.C - 2.f * ((PM).x * px.C + (PM).y * py.C + (PM).z * pz.C); \
    dd_ = fmaxf(dd_, 0.f); \
    float l0_ = (dd_ <= th.C) ? a1v_ : 0.f; \
    S += __expf(l0_); }
  for (int it = 0; it < 16; ++it) {
    const int n0 = (it << 8) + (lane << 2);
    LKPL(kb, n0)
    const float4 px = *(const float4*)(xk + 0*NN + n0);
    const float4 py = *(const float4*)(xk + 1*NN + n0);
    const float4 pz = *(const float4*)(xk + 2*NN + n0);
    const float4 pw = *(const float4*)(xk + 3*NN + n0);
    const float4 ic = *(const float4*)(ics1 + b * NN + n0);
    const float4 th = *(const float4*)(thr + b * NN + n0);
    P3C(sA, ma0,ma1,ma2,ma3, pmA, rA, x)
    P3C(sA, ma0,ma1,ma2,ma3, pmA, rA, y)
    P3C(sA, ma0,ma1,ma2,ma3, pmA, rA, z)
    P3C(sA, ma0,ma1,ma2,ma3, pmA, rA, w)
    P3C(sB, mb0,mb1,mb2,mb3, pmB, rB, x)
    P3C(sB, mb0,mb1,mb2,mb3, pmB, rB, y)
    P3C(sB, mb0,mb1,mb2,mb3, pmB, rB, z)
    P3C(sB, mb0,mb1,mb2,mb3, pmB, rB, w)
    P3C(sC, mc0,mc1,mc2,mc3, pmC, rC, x)
    P3C(sC, mc0,mc1,mc2,mc3, pmC, rC, y)
    P3C(sC, mc0,mc1,mc2,mc3, pmC, rC, z)
    P3C(sC, mc0,mc1,mc2,mc3, pmC, rC, w)
    P3C(sD, md0,md1,md2,md3, pmD, rD, x)
    P3C(sD, md0,md1,md2,md3, pmD, rD, y)
    P3C(sD, md0,md1,md2,md3, pmD, rD, z)
    P3C(sD, md0,md1,md2,md3, pmD, rD, w)
  }
#undef P3C
  WRED(sA) WRED(sB) WRED(sC) WRED(sD)
  if (lane == 0) {
    irs2[b * NN + mA] = rcpf_(sA);
    irs2[b * NN + mB] = rcpf_(sB);
    irs2[b * NN + mC] = rcpf_(sC);
    irs2[b * NN + mD] = rcpf_(sD);
  }
}

__global__ __launch_bounds__(256) void k7_gma(
    const float* __restrict__ qt, const float* __restrict__ xyz4,
    const unsigned short* __restrict__ xvb,
    const float* __restrict__ irs1, const float* __restrict__ irs2,
    const float* __restrict__ ics1, const float* __restrict__ thr,
    float* __restrict__ g1, float* __restrict__ g2, float* __restrict__ cs2) {
  const int tid = threadIdx.x;
  const int bid = blockIdx.x;
  const int msl = bid & 7;
  const int nb = (bid >> 3) & 63;
  const int b = bid >> 9;
  const int n0 = nb << 6;
  const int mstart = msl << 9;
  __shared__ __align__(16) unsigned short attns1[64 * 72];
  __shared__ __align__(16) unsigned short attns2[64 * 72];
  __shared__ __align__(16) unsigned short xvs[64 * 72];
  const float* qb = qt + (size_t)b * NN * 16;
  const float* pb = xyz4 + (size_t)b * NN * 4;
  const int ni = tid & 63, aw = tid >> 6;
  const int na = n0 + ni;
  const float* qnp = qb + (size_t)na * 16;
  LQROW(q, qnp)
  const float4 pn = *(const float4*)(pb + (size_t)na * 4);
  const float ics1n = ics1[b * NN + na];
  const float thr_n = thr[b * NN + na];
  const int lane = tid & 63, wv = tid >> 6;
  const int lr = lane & 15, quad = lane >> 4;
  const int nw = wv << 4;
  f32x4v acc0 = {0,0,0,0}, acc1 = {0,0,0,0}, acc2 = {0,0,0,0}, acc3 = {0,0,0,0};
  f32x4v d0 = {0,0,0,0}, d1 = {0,0,0,0}, d2 = {0,0,0,0}, d3 = {0,0,0,0};
  float csacc = 0.f;
#define COMPA(MOFF, D1, D2) { \
    const int m_ = __builtin_amdgcn_readfirstlane(mw + (MOFF)); \
    const float* qm_ = qb + (size_t)m_ * 16; \
    LQROW(wq, qm_) \
    float corr_ = DOT16M(q0, q1, q2, q3, wq0, wq1, wq2, wq3); \
    const float4 pm_ = *(const float4*)(pb + (size_t)m_ * 4); \
    float a1v_ = __expf(fminf(corr_, 80.f)) * irs1[b * NN + m_] * ics1n; \
    float dd_ = pm_.w + pn.w - 2.f * (pm_.x * pn.x + pm_.y * pn.y + pm_.z * pn.z); \
    dd_ = fmaxf(dd_, 0.f); \
    float l0_ = (dd_ <= thr_n) ? a1v_ : 0.f; \
    float l2n_ = __expf(l0_) * irs2[b * NN + m_]; \
    D1 = f2bf(a1v_); D2 = f2bf(l2n_); csacc += l2n_; }
  for (int mt = 0; mt < 8; ++mt) {
    const int m0 = mstart + (mt << 6);
    __syncthreads();
    {
      const int c = tid >> 2, part = tid & 3;
      const unsigned short* src = xvb + ((size_t)b * 64 + c) * NN + m0 + part * 16;
      unsigned short* dst = xvs + c * 72 + part * 16;
      *(uint4*)dst = *(const uint4*)src;
      *(uint4*)(dst + 8) = *(const uint4*)(src + 8);
    }
    const int mw = m0 + (aw << 4);
#pragma unroll
    for (int g = 0; g < 4; ++g) {
      ushort4 u1, u2;
      COMPA(g * 4 + 0, u1.x, u2.x)
      COMPA(g * 4 + 1, u1.y, u2.y)
      COMPA(g * 4 + 2, u1.z, u2.z)
      COMPA(g * 4 + 3, u1.w, u2.w)
      *(ushort4*)(attns1 + ni * 72 + (aw << 4) + (g << 2)) = u1;
      *(ushort4*)(attns2 + ni * 72 + (aw << 4) + (g << 2)) = u2;
    }
    __syncthreads();
#pragma unroll
    for (int h = 0; h < 2; ++h) {
      const bf16x8 a1 = *(const bf16x8*)(attns1 + (nw + lr) * 72 + h * 32 + quad * 8);
      const bf16x8 a2 = *(const bf16x8*)(attns2 + (nw + lr) * 72 + h * 32 + quad * 8);
      const bf16x8 b0 = *(const bf16x8*)(xvs + (lr) * 72 + h * 32 + quad * 8);
      const bf16x8 b1 = *(const bf16x8*)(xvs + (16 + lr) * 72 + h * 32 + quad * 8);
      const bf16x8 b2 = *(const bf16x8*)(xvs + (32 + lr) * 72 + h * 32 + quad * 8);
      const bf16x8 b3 = *(const bf16x8*)(xvs + (48 + lr) * 72 + h * 32 + quad * 8);
      acc0 = __builtin_amdgcn_mfma_f32_16x16x32_bf16(a1, b0, acc0, 0, 0, 0);
      acc1 = __builtin_amdgcn_mfma_f32_16x16x32_bf16(a1, b1, acc1, 0, 0, 0);
      acc2 = __builtin_amdgcn_mfma_f32_16x16x32_bf16(a1, b2, acc2, 0, 0, 0);
      acc3 = __builtin_amdgcn_mfma_f32_16x16x32_bf16(a1, b3, acc3, 0, 0, 0);
      d0 = __builtin_amdgcn_mfma_f32_16x16x32_bf16(a2, b0, d0, 0, 0, 0);
      d1 = __builtin_amdgcn_mfma_f32_16x16x32_bf16(a2, b1, d1, 0, 0, 0);
      d2 = __builtin_amdgcn_mfma_f32_16x16x32_bf16(a2, b2, d2, 0, 0, 0);
      d3 = __builtin_amdgcn_mfma_f32_16x16x32_bf16(a2, b3, d3, 0, 0, 0);
    }
  }
#undef COMPA
  atomicAdd(&cs2[b * NN + na], csacc);
#define EPI(ACC, DST, CT) { \
    float* g_ = (DST) + ((size_t)b * NN + n0 + nw + (quad << 2)) * 64 + (CT) * 16 + lr; \
    atomicAdd(g_ + 0,   ACC[0]); \
    atomicAdd(g_ + 64,  ACC[1]); \
    atomicAdd(g_ + 128, ACC[2]); \
    atomicAdd(g_ + 192, ACC[3]); }
  EPI(acc0, g1, 0) EPI(acc1, g1, 1) EPI(acc2, g1, 2) EPI(acc3, g1, 3)
  EPI(d0, g2, 0) EPI(d1, g2, 1) EPI(d2, g2, 2) EPI(d3, g2, 3)
#undef EPI
}

// ============ materialized-exp path (used iff ws_size permits) ============

// P1W: like p1 but stores a0[m][n]=bf16(exp(corr)) and sums the ROUNDED values.
__global__ __launch_bounds__(256) void p1w_rs1(
    const float* __restrict__ qt, const float* __restrict__ qk,
    float* __restrict__ irs1, unsigned short* __restrict__ a0g) {
  const int tid = threadIdx.x;
  const int b = blockIdx.x >> 8;
  const int m0 = (blockIdx.x & 255) << 4;
  const int w = tid >> 6, lane = tid & 63;
  const float* qb = qt + (size_t)b * NN * 16;
  const float* kb = qk + (size_t)b * 16 * NN;
  unsigned short* ab = a0g + (size_t)b * NN * NN;
  const int mA = m0 + w, mB = m0 + w + 4, mC = m0 + w + 8, mD = m0 + w + 12;
  LQROW(ma, qb + (size_t)mA * 16)
  LQROW(mb, qb + (size_t)mB * 16)
  LQROW(mc, qb + (size_t)mC * 16)
  LQROW(md, qb + (size_t)mD * 16)
  float sA = 0.f, sB = 0.f, sC = 0.f, sD = 0.f;
#define P1E(S, U, UC, M0,M1,M2,M3, C) { \
    float e_ = __expf(fminf(DOTC(M0,M1,M2,M3,C), 80.f)); \
    unsigned short us_ = f2bf(e_); U.UC = us_; S += bf2f(us_); }
  for (int it = 0; it < 16; ++it) {
    const int n0 = (it << 8) + (lane << 2);
    LKPL(kb, n0)
    ushort4 uA, uB, uC, uD;
    P1E(sA, uA, x, ma0,ma1,ma2,ma3, x) P1E(sA, uA, y, ma0,ma1,ma2,ma3, y)
    P1E(sA, uA, z, ma0,ma1,ma2,ma3, z) P1E(sA, uA, w, ma0,ma1,ma2,ma3, w)
    P1E(sB, uB, x, mb0,mb1,mb2,mb3, x) P1E(sB, uB, y, mb0,mb1,mb2,mb3, y)
    P1E(sB, uB, z, mb0,mb1,mb2,mb3, z) P1E(sB, uB, w, mb0,mb1,mb2,mb3, w)
    P1E(sC, uC, x, mc0,mc1,mc2,mc3, x) P1E(sC, uC, y, mc0,mc1,mc2,mc3, y)
    P1E(sC, uC, z, mc0,mc1,mc2,mc3, z) P1E(sC, uC, w, mc0,mc1,mc2,mc3, w)
    P1E(sD, uD, x, md0,md1,md2,md3, x) P1E(sD, uD, y, md0,md1,md2,md3, y)
    P1E(sD, uD, z, md0,md1,md2,md3, z) P1E(sD, uD, w, md0,md1,md2,md3, w)
    *(ushort4*)(ab + (size_t)mA * NN + n0) = uA;
    *(ushort4*)(ab + (size_t)mB * NN + n0) = uB;
    *(ushort4*)(ab + (size_t)mC * NN + n0) = uC;
    *(ushort4*)(ab + (size_t)mD * NN + n0) = uD;
  }
#undef P1E
  WRED(sA) WRED(sB) WRED(sC) WRED(sD)
  if (lane == 0) {
    irs1[b * NN + mA] = rcpf_(sA);
    irs1[b * NN + mB] = rcpf_(sB);
    irs1[b * NN + mC] = rcpf_(sC);
    irs1[b * NN + mD] = rcpf_(sD);
  }
}

// P2R: cs1 via SYMMETRY of corr: cs1[n] = sum_m a0[n][m]*irs1[m].
// Pure coalesced row-dot over the materialized bf16 a0 (replaces the full
// QK^T recompute of p2_cs1 on the big path).
__global__ __launch_bounds__(256) void p2r_cs1(
    const unsigned short* __restrict__ a0g, const float* __restrict__ irs1,
    float* __restrict__ ics1) {
  const int tid = threadIdx.x;
  const int w = tid >> 6, l = tid & 63;
  const int bi = blockIdx.x;                 // 0..2047
  const int b = bi >> 10;
  const int n = ((bi & 1023) << 2) + w;      // 4 rows per block, 1 per wave
  const unsigned short* row = a0g + ((size_t)b * NN + n) * NN;
  const float* ir = irs1 + b * NN;
  float s = 0.f;
#pragma unroll
  for (int it = 0; it < 8; ++it) {
    const int m = (it << 9) + (l << 3);
    const uint4 u = *(const uint4*)(row + m);
    const float4 i0 = *(const float4*)(ir + m);
    const float4 i1 = *(const float4*)(ir + m + 4);
    s = fmaf(bf2f((unsigned short)(u.x & 0xffffu)), i0.x, s);
    s = fmaf(bf2f((unsigned short)(u.x >> 16)),     i0.y, s);
    s = fmaf(bf2f((unsigned short)(u.y & 0xffffu)), i0.z, s);
    s = fmaf(bf2f((unsigned short)(u.y >> 16)),     i0.w, s);
    s = fmaf(bf2f((unsigned short)(u.z & 0xffffu)), i1.x, s);
    s = fmaf(bf2f((unsigned short)(u.z >> 16)),     i1.y, s);
    s = fmaf(bf2f((unsigned short)(u.w & 0xffffu)), i1.z, s);
    s = fmaf(bf2f((unsigned short)(u.w >> 16)),     i1.w, s);
  }
  WRED(s)
  if (l == 0) ics1[b * NN + n] = rcpf_(1e-9f + s);
}

// P3W: reads a0 rows (no corr recompute), stores ae[m][n]=bf16(exp(l0)),
// sums ROUNDED values for irs2.
__global__ __launch_bounds__(256) void p3w_rs2(
    const float* __restrict__ xyz4, const float* __restrict__ xyzk,
    const float* __restrict__ irs1, const float* __restrict__ ics1,
    const float* __restrict__ thr, float* __restrict__ irs2,
    const unsigned short* __restrict__ a0g, unsigned short* __restrict__ aeg) {
  const int tid = threadIdx.x;
  const int b = blockIdx.x >> 8;
  const int m0 = (blockIdx.x & 255) << 4;
  const int w = tid >> 6, lane = tid & 63;
  const float* xk = xyzk + (size_t)b * 4 * NN;
  const unsigned short* ab = a0g + (size_t)b * NN * NN;
  unsigned short* eb = aeg + (size_t)b * NN * NN;
  const int mA = m0 + w, mB = m0 + w + 4, mC = m0 + w + 8, mD = m0 + w + 12;
  const float4 pmA = *(const float4*)(xyz4 + ((size_t)b * NN + mA) * 4);
  const float4 pmB = *(const float4*)(xyz4 + ((size_t)b * NN + mB) * 4);
  const float4 pmC = *(const float4*)(xyz4 + ((size_t)b * NN + mC) * 4);
  const float4 pmD = *(const float4*)(xyz4 + ((size_t)b * NN + mD) * 4);
  const float rA = irs1[b * NN + mA];
  const float rB = irs1[b * NN + mB];
  const float rC = irs1[b * NN + mC];
  const float rD = irs1[b * NN + mD];
  float sA = 0.f, sB = 0.f, sC = 0.f, sD = 0.f;
#define P3W(S, RU, EU, UC, PM, R, C) { \
    float a1v_ = bf2f(RU.UC) * (R) * ic.C; \
    float dd_ = (PM).w + pw.C - 2.f * ((PM).x * px.C + (PM).y * py.C + (PM).z * pz.C); \
    dd_ = fmaxf(dd_, 0.f); \
    float l0_ = (dd_ <= th.C) ? a1v_ : 0.f; \
    unsigned short us_ = f2bf(__expf(l0_)); EU.UC = us_; S += bf2f(us_); }
  for (int it = 0; it < 16; ++it) {
    const int n0 = (it << 8) + (lane << 2);
    const float4 px = *(const float4*)(xk + 0*NN + n0);
    const float4 py = *(const float4*)(xk + 1*NN + n0);
    const float4 pz = *(const float4*)(xk + 2*NN + n0);
    const float4 pw = *(const float4*)(xk + 3*NN + n0);
    const float4 ic = *(const float4*)(ics1 + b * NN + n0);
    const float4 th = *(const float4*)(thr + b * NN + n0);
    const ushort4 rA4 = *(const ushort4*)(ab + (size_t)mA * NN + n0);
    const ushort4 rB4 = *(const ushort4*)(ab + (size_t)mB * NN + n0);
    const ushort4 rC4 = *(const ushort4*)(ab + (size_t)mC * NN + n0);
    const ushort4 rD4 = *(const ushort4*)(ab + (size_t)mD * NN + n0);
    ushort4 eA, eB, eC, eD;
    P3W(sA, rA4, eA, x, pmA, rA, x) P3W(sA, rA4, eA, y, pmA, rA, y)
    P3W(sA, rA4, eA, z, pmA, rA, z) P3W(sA, rA4, eA, w, pmA, rA, w)
    P3W(sB, rB4, eB, x, pmB, rB, x) P3W(sB, rB4, eB, y, pmB, rB, y)
    P3W(sB, rB4, eB, z, pmB, rB, z) P3W(sB, rB4, eB, w, pmB, rB, w)
    P3W(sC, rC4, eC, x, pmC, rC, x) P3W(sC, rC4, eC, y, pmC, rC, y)
    P3W(sC, rC4, eC, z, pmC, rC, z) P3W(sC, rC4, eC, w, pmC, rC, w)
    P3W(sD, rD4, eD, x, pmD, rD, x) P3W(sD, rD4, eD, y, pmD, rD, y)
    P3W(sD, rD4, eD, z, pmD, rD, z) P3W(sD, rD4, eD, w, pmD, rD, w)
    *(ushort4*)(eb + (size_t)mA * NN + n0) = eA;
    *(ushort4*)(eb + (size_t)mB * NN + n0) = eB;
    *(ushort4*)(eb + (size_t)mC * NN + n0) = eC;
    *(ushort4*)(eb + (size_t)mD * NN + n0) = eD;
  }
#undef P3W
  WRED(sA) WRED(sB) WRED(sC) WRED(sD)
  if (lane == 0) {
    irs2[b * NN + mA] = rcpf_(sA);
    irs2[b * NN + mB] = rcpf_(sB);
    irs2[b * NN + mC] = rcpf_(sC);
    irs2[b * NN + mD] = rcpf_(sD);
  }
}

// K7N: latency-optimized GMA. Phase A is a wide-load staging pass:
//  - ics1[n] factored out of the m-contraction (applied in k8)  ->
//    per-element work is one irs-scale, irs loads are per-row coalesced floats
//  - 6x16B coalesced global loads/thread (wave covers 8 full 128B row segs)
//  - next tile's loads issued before this tile's MFMA phase (T14 split)
//  - LDS stride 64 + XOR swizzle (byte ^= (row&7)<<4): phase-B b128 reads at
//    bandwidth minimum (was 8-way conflicted at stride 72)
//  - cs2 reduced from a2 fragments in phase B (2 shfl_xor), not per-element
__global__ __launch_bounds__(256) void k7n_gma(
    const unsigned short* __restrict__ a0g, const unsigned short* __restrict__ aeg,
    const unsigned short* __restrict__ xvb,
    const float* __restrict__ irs1, const float* __restrict__ irs2,
    float* __restrict__ g1, float* __restrict__ g2, float* __restrict__ cs2) {
  const int tid = threadIdx.x;
  const int bid = blockIdx.x;
  const int msl = bid & 7;
  const int nb = (bid >> 3) & 63;
  const int b = bid >> 9;
  const int n0 = nb << 6;
  const int mstart = msl << 9;
  __shared__ __align__(16) unsigned short attns1[64 * 64];
  __shared__ __align__(16) unsigned short attns2[64 * 64];
  __shared__ __align__(16) unsigned short xvs[64 * 64];
  const unsigned short* ab = a0g + (size_t)b * NN * NN;
  const unsigned short* ebp = aeg + (size_t)b * NN * NN;
  const float* irs1b = irs1 + b * NN;
  const float* irs2b = irs2 + b * NN;
  const int w = tid >> 6, l = tid & 63;
  // phase-A load mapping: wave w stages rows w*16..w*16+15; lane covers 2
  // consecutive rows (even/odd pair -> packed b32 LDS writes)
  const int lrow0 = (w << 4) + ((l >> 3) << 1);   // even row; +1 = odd row
  const int nc8 = (l & 7) << 3;                   // local n base (8 cols)
  const int gcol = n0 + nc8;
  // xv staging mapping
  const int xc = tid >> 2, xpart = tid & 3;
  const unsigned short* xvp = xvb + ((size_t)b * 64 + xc) * NN;
  // phase-B mapping
  const int lr = l & 15, quad = l >> 4;
  const int nw = w << 4;
  f32x4v acc0 = {0,0,0,0}, acc1 = {0,0,0,0}, acc2 = {0,0,0,0}, acc3 = {0,0,0,0};
  f32x4v d0 = {0,0,0,0}, d1 = {0,0,0,0}, d2 = {0,0,0,0}, d3 = {0,0,0,0};
  float csp = 0.f;

  uint4 pa0, pa1, pe0, pe1, pv0, pv1;
  float r1a, r1b, r2a, r2b;

#define ISSUE(MT) { \
    const int m0_ = mstart + ((MT) << 6); \
    const size_t ra_ = (size_t)(m0_ + lrow0) * NN + gcol; \
    pa0 = *(const uint4*)(ab + ra_); \
    pa1 = *(const uint4*)(ab + ra_ + NN); \
    pe0 = *(const uint4*)(ebp + ra_); \
    pe1 = *(const uint4*)(ebp + ra_ + NN); \
    pv0 = *(const uint4*)(xvp + m0_ + (xpart << 4)); \
    pv1 = *(const uint4*)(xvp + m0_ + (xpart << 4) + 8); \
    r1a = irs1b[m0_ + lrow0]; r1b = irs1b[m0_ + lrow0 + 1]; \
    r2a = irs2b[m0_ + lrow0]; r2b = irs2b[m0_ + lrow0 + 1]; }

// convert a pair of rows' element J (u16 halves of dwords D0/D1), scale by
// R0/R1, pack even/odd rows into one dword, swizzled LDS store
#define CVW(D0, D1, SH, J, R0, R1, ARR) { \
    const float v0_ = bf2f((unsigned short)(((D0) >> (SH)) & 0xffffu)) * (R0); \
    const float v1_ = bf2f((unsigned short)(((D1) >> (SH)) & 0xffffu)) * (R1); \
    const unsigned pk_ = (unsigned)f2bf(v0_) | ((unsigned)f2bf(v1_) << 16); \
    *(unsigned*)((char*)(ARR) + ((((nc8 + (J)) << 7) + (lrow0 << 1)) ^ ((J) << 4))) = pk_; }

#define WR8(U0, U1, R0, R1, ARR) \
    CVW(U0.x, U1.x, 0,  0, R0, R1, ARR) CVW(U0.x, U1.x, 16, 1, R0, R1, ARR) \
    CVW(U0.y, U1.y, 0,  2, R0, R1, ARR) CVW(U0.y, U1.y, 16, 3, R0, R1, ARR) \
    CVW(U0.z, U1.z, 0,  4, R0, R1, ARR) CVW(U0.z, U1.z, 16, 5, R0, R1, ARR) \
    CVW(U0.w, U1.w, 0,  6, R0, R1, ARR) CVW(U0.w, U1.w, 16, 7, R0, R1, ARR)

#define LDSW(ARR, ROW, H, Q) \
    (*(const bf16x8*)((const char*)(ARR) + \
      ((((ROW) << 7) + ((H) << 6) + ((Q) << 4)) ^ (((ROW) & 7) << 4))))

  ISSUE(0)
  for (int mt = 0; mt < 8; ++mt) {
    __syncthreads();
    // stage current regs -> LDS (scaled attn tiles, raw xv tile)
    WR8(pa0, pa1, r1a, r1b, attns1)
    WR8(pe0, pe1, r2a, r2b, attns2)
    {
      const int xb = (xc << 7) + (xpart << 5);
      const int xs = (xc & 7) << 4;
      *(uint4*)((char*)xvs + ((xb) ^ xs)) = pv0;
      *(uint4*)((char*)xvs + ((xb + 16) ^ xs)) = pv1;
    }
    __syncthreads();
    if (mt < 7) ISSUE(mt + 1)   // prefetch flies under the MFMA phase
#pragma unroll
    for (int h = 0; h < 2; ++h) {
      const bf16x8 a1 = LDSW(attns1, nw + lr, h, quad);
      const bf16x8 a2 = LDSW(attns2, nw + lr, h, quad);
      const bf16x8 b0 = LDSW(xvs, lr, h, quad);
      const bf16x8 b1 = LDSW(xvs, 16 + lr, h, quad);
      const bf16x8 b2 = LDSW(xvs, 32 + lr, h, quad);
      const bf16x8 b3 = LDSW(xvs, 48 + lr, h, quad);
      acc0 = __builtin_amdgcn_mfma_f32_16x16x32_bf16(a1, b0, acc0, 0, 0, 0);
      acc1 = __builtin_amdgcn_mfma_f32_16x16x32_bf16(a1, b1, acc1, 0, 0, 0);
      acc2 = __builtin_amdgcn_mfma_f32_16x16x32_bf16(a1, b2, acc2, 0, 0, 0);
      acc3 = __builtin_amdgcn_mfma_f32_16x16x32_bf16(a1, b3, acc3, 0, 0, 0);
      d0 = __builtin_amdgcn_mfma_f32_16x16x32_bf16(a2, b0, d0, 0, 0, 0);
      d1 = __builtin_amdgcn_mfma_f32_16x16x32_bf16(a2, b1, d1, 0, 0, 0);
      d2 = __builtin_amdgcn_mfma_f32_16x16x32_bf16(a2, b2, d2, 0, 0, 0);
      d3 = __builtin_amdgcn_mfma_f32_16x16x32_bf16(a2, b3, d3, 0, 0, 0);
      // cs2 partial: a2 row (nw+lr) over this lane's 8 m's
#pragma unroll
      for (int j = 0; j < 8; ++j) csp += bf2f((unsigned short)a2[j]);
    }
  }
#undef ISSUE
#undef CVW
#undef WR8
#undef LDSW
  // reduce cs2 over quads (lanes lr, lr+16, lr+32, lr+48)
  csp += __shfl_xor(csp, 32);
  csp += __shfl_xor(csp, 16);
  if (quad == 0) atomicAdd(&cs2[b * NN + n0 + nw + lr], csp);
#define EPI(ACC, DST, CT) { \
    float* g_ = (DST) + ((size_t)b * NN + n0 + nw + (quad << 2)) * 64 + (CT) * 16 + lr; \
    atomicAdd(g_ + 0,   ACC[0]); \
    atomicAdd(g_ + 64,  ACC[1]); \
    atomicAdd(g_ + 128, ACC[2]); \
    atomicAdd(g_ + 192, ACC[3]); }
  EPI(acc0, g1, 0) EPI(acc1, g1, 1) EPI(acc2, g1, 2) EPI(acc3, g1, 3)
  EPI(d0, g2, 0) EPI(d1, g2, 1) EPI(d2, g2, 2) EPI(d3, g2, 3)
#undef EPI
}

// ===================== common p2 / k8 / k9 =====================

__global__ __launch_bounds__(256) void p2_cs1(
    const float* __restrict__ qt, const float* __restrict__ qk,
    const float* __restrict__ irs1, float* __restrict__ ics1) {
  const int tid = threadIdx.x;
  const int b = blockIdx.x >> 8;
  const int n0t = (blockIdx.x & 255) << 4;
  const int w = tid >> 6, lane = tid & 63;
  const float* qb = qt + (size_t)b * NN * 16;
  const float* kb = qk + (size_t)b * 16 * NN;
  const int nA = n0t + w, nB = n0t + w + 4, nC = n0t + w + 8, nD = n0t + w + 12;
  LQROW(na, qb + (size_t)nA * 16)
  LQROW(nb, qb + (size_t)nB * 16)
  LQROW(nc, qb + (size_t)nC * 16)
  LQROW(nd, qb + (size_t)nD * 16)
  float sA = 0.f, sB = 0.f, sC = 0.f, sD = 0.f;
  for (int it = 0; it < 16; ++it) {
    const int m0 = (it << 8) + (lane << 2);
    LKPL(kb, m0)
    const float4 r1 = *(const float4*)(irs1 + b * NN + m0);
    sA = fmaf(__expf(fminf(DOTC(na0,na1,na2,na3,x), 80.f)), r1.x, sA);
    sA = fmaf(__expf(fminf(DOTC(na0,na1,na2,na3,y), 80.f)), r1.y, sA);
    sA = fmaf(__expf(fminf(DOTC(na0,na1,na2,na3,z), 80.f)), r1.z, sA);
    sA = fmaf(__expf(fminf(DOTC(na0,na1,na2,na3,w), 80.f)), r1.w, sA);
    sB = fmaf(__expf(fminf(DOTC(nb0,nb1,nb2,nb3,x), 80.f)), r1.x, sB);
    sB = fmaf(__expf(fminf(DOTC(nb0,nb1,nb2,nb3,y), 80.f)), r1.y, sB);
    sB = fmaf(__expf(fminf(DOTC(nb0,nb1,nb2,nb3,z), 80.f)), r1.z, sB);
    sB = fmaf(__expf(fminf(DOTC(nb0,nb1,nb2,nb3,w), 80.f)), r1.w, sB);
    sC = fmaf(__expf(fminf(DOTC(nc0,nc1,nc2,nc3,x), 80.f)), r1.x, sC);
    sC = fmaf(__expf(fminf(DOTC(nc0,nc1,nc2,nc3,y), 80.f)), r1.y, sC);
    sC = fmaf(__expf(fminf(DOTC(nc0,nc1,nc2,nc3,z), 80.f)), r1.z, sC);
    sC = fmaf(__expf(fminf(DOTC(nc0,nc1,nc2,nc3,w), 80.f)), r1.w, sC);
    sD = fmaf(__expf(fminf(DOTC(nd0,nd1,nd2,nd3,x), 80.f)), r1.x, sD);
    sD = fmaf(__expf(fminf(DOTC(nd0,nd1,nd2,nd3,y), 80.f)), r1.y, sD);
    sD = fmaf(__expf(fminf(DOTC(nd0,nd1,nd2,nd3,z), 80.f)), r1.z, sD);
    sD = fmaf(__expf(fminf(DOTC(nd0,nd1,nd2,nd3,w), 80.f)), r1.w, sD);
  }
  WRED(sA) WRED(sB) WRED(sC) WRED(sD)
  if (lane == 0) {
    ics1[b * NN + nA] = rcpf_(1e-9f + sA);
    ics1[b * NN + nB] = rcpf_(1e-9f + sB);
    ics1[b * NN + nC] = rcpf_(1e-9f + sC);
    ics1[b * NN + nD] = rcpf_(1e-9f + sD);
  }
}

__global__ __launch_bounds__(256) void k8_res(
    const void* __restrict__ mot, const void* __restrict__ wt,
    const void* __restrict__ bt, const float* __restrict__ flag,
    float* __restrict__ g1_res, const float* __restrict__ g2,
    const float* __restrict__ cs2, float* __restrict__ gn,
    const float* __restrict__ ics1, int g1mode) {
  const bool f32 = flag[0] > 0.5f;
  const int tid = threadIdx.x;
  const int bid = blockIdx.x;
  const int b = bid >> 9;
  const int n0 = (bid & 511) << 3;
  __shared__ float wtT[64 * 65];
  __shared__ float bts[64];
  __shared__ float md[8 * 64];
  __shared__ float gs[8], gss[8];
  for (int i = tid; i < 4096; i += 256) {
    int o = i & 63, c = i >> 6;
    wtT[c * 65 + o] = ldin(wt, o * 64 + c, f32);
  }
  if (tid < 64) bts[tid] = ldin(bt, tid, f32);
  if (tid < 8) { gs[tid] = 0.f; gss[tid] = 0.f; }
#pragma unroll
  for (int r = 0; r < 2; ++r) {
    const int idx = tid * 2 + r;
    const int c = idx & 63, nl = idx >> 6;
    const size_t gi = ((size_t)b * NN + n0 + nl) * 64 + c;
    const float ics2n = rcpf_(1e-9f + cs2[b * NN + n0 + nl]);
    float g1v = g1_res[gi];
    if (g1mode) g1v *= ics1[b * NN + n0 + nl];
    float gmav = fmaf(g2[gi], ics2n, g1v);
    md[nl * 64 + c] = ldin(mot, ((size_t)b * 64 + c) * NN + n0 + nl, f32) - gmav;
  }
  __syncthreads();
  const int o = tid & 63, ng = tid >> 6;
  const int nl0 = ng * 2, nl1 = ng * 2 + 1;
  float a0 = bts[o], a1 = bts[o];
#pragma unroll 8
  for (int c = 0; c < 64; ++c) {
    float w = wtT[c * 65 + o];
    a0 = fmaf(w, md[nl0 * 64 + c], a0);
    a1 = fmaf(w, md[nl1 * 64 + c], a1);
  }
  g1_res[((size_t)b * NN + n0 + nl0) * 64 + o] = a0;
  g1_res[((size_t)b * NN + n0 + nl1) * 64 + o] = a1;
  atomicAdd(&gs[o >> 3], a0 + a1);
  atomicAdd(&gss[o >> 3], a0 * a0 + a1 * a1);
  __syncthreads();
  if (tid < 8) atomicAdd(&gn[b * 8 + tid], gs[tid]);
  else if (tid < 16) atomicAdd(&gn[16 + b * 8 + (tid - 8)], gss[tid - 8]);
}

__global__ __launch_bounds__(256) void k9_out(
    const float* __restrict__ res, const float* __restrict__ gn,
    const void* __restrict__ mot,
    const void* __restrict__ gnw, const void* __restrict__ gnb,
    const void* __restrict__ pa, const void* __restrict__ al,
    const float* __restrict__ flag, void* __restrict__ out) {
  const bool f32 = flag[0] > 0.5f;
  const int idx = blockIdx.x * 256 + threadIdx.x;
  const int n = idx & 4095;
  const int c = (idx >> 12) & 63;
  const int b = idx >> 18;
  const int g = c >> 3;
  const float inv_cnt = 1.f / 32768.f;
  float mean = gn[b * 8 + g] * inv_cnt;
  float var = gn[16 + b * 8 + g] * inv_cnt - mean * mean;
  var = fmaxf(var, 0.f);
  float rstd = rsqrtf(var + 1e-5f);
  float r = res[((size_t)b * NN + n) * 64 + c];
  float y = (r - mean) * rstd * ldin(gnw, c, f32) + ldin(gnb, c, f32);
  float slope = ldin(pa, 0, f32);
  y = (y >= 0.f) ? y : slope * y;
  float o = ldin(al, 0, f32) * y + ldin(mot, idx, f32);
  if (f32) ((float*)out)[idx] = o;
  else     ((__hip_bfloat16*)out)[idx] = __float2bfloat16(o);
}

extern "C" void kernel_launch(void* const* d_in, const int* in_sizes, int n_in,
                              void* d_out, int out_size, void* d_ws, size_t ws_size,
                              hipStream_t stream) {
  const void* ctx = d_in[0];
  const void* mot = d_in[1];
  const void* xyz = d_in[2];
  const void* wqk = d_in[3];
  const void* wv  = d_in[4];
  const void* bv  = d_in[5];
  const void* wt  = d_in[6];
  const void* bt  = d_in[7];
  const void* gnw = d_in[8];
  const void* gnb = d_in[9];
  const void* pa  = d_in[10];
  const void* al  = d_in[11];
  float* ws = (float*)d_ws;
  const bool big = ws_size >= (size_t)FULL_F * sizeof(float);

  if (ws_size < (size_t)WS_TOTAL * sizeof(float))
    fprintf(stderr, "[gma3d] WARNING ws_size=%zu < needed %zu\n",
            ws_size, (size_t)WS_TOTAL * sizeof(float));

  hipMemsetAsync(ws + OFF_SUMS, 0, (size_t)ZERO_F * sizeof(float), stream);

  k0_detect<<<1, 256, 0, stream>>>((const unsigned short*)ctx, ws + OFF_FLAG);
  k1_q_xyz<<<32, 256, 0, stream>>>(ctx, xyz, wqk, ws + OFF_FLAG,
                                   ws + OFF_QT, ws + OFF_QK,
                                   ws + OFF_XYZ4, ws + OFF_XYZK, ws + OFF_SUMS);
  k2_xv<<<128, 256, 0, stream>>>(mot, wv, bv, ws + OFF_FLAG,
                                 (unsigned short*)(ws + OFF_XVB));
  k2b_thr<<<32, 256, 0, stream>>>(ws + OFF_XYZ4, ws + OFF_SUMS, ws + OFF_THR);

  if (big) {
    unsigned short* a0 = (unsigned short*)(ws + OFF_A0);
    unsigned short* ae = (unsigned short*)(ws + OFF_AE);
    p1w_rs1<<<512, 256, 0, stream>>>(ws + OFF_QT, ws + OFF_QK, ws + OFF_IRS1, a0);
    p2r_cs1<<<2048, 256, 0, stream>>>(a0, ws + OFF_IRS1, ws + OFF_ICS1);
    p3w_rs2<<<512, 256, 0, stream>>>(ws + OFF_XYZ4, ws + OFF_XYZK,
                                     ws + OFF_IRS1, ws + OFF_ICS1, ws + OFF_THR,
                                     ws + OFF_IRS2, a0, ae);
    k7n_gma<<<1024, 256, 0, stream>>>(a0, ae,
                                      (const unsigned short*)(ws + OFF_XVB),
                                      ws + OFF_IRS1, ws + OFF_IRS2,
                                      ws + OFF_GMA, ws + OFF_G2, ws + OFF_CS2);
    k8_res<<<1024, 256, 0, stream>>>(mot, wt, bt, ws + OFF_FLAG,
                                     ws + OFF_GMA, ws + OFF_G2, ws + OFF_CS2,
                                     ws + OFF_GN, ws + OFF_ICS1, 1);
  } else {
    p1_rs1<<<512, 256, 0, stream>>>(ws + OFF_QT, ws + OFF_QK, ws + OFF_IRS1);
    p2_cs1<<<512, 256, 0, stream>>>(ws + OFF_QT, ws + OFF_QK, ws + OFF_IRS1, ws + OFF_ICS1);
    p3_rs2<<<512, 256, 0, stream>>>(ws + OFF_QT, ws + OFF_QK,
                                    ws + OFF_XYZ4, ws + OFF_XYZK,
                                    ws + OFF_IRS1, ws + OFF_ICS1, ws + OFF_THR,
                                    ws + OFF_IRS2);
    k7_gma<<<1024, 256, 0, stream>>>(ws + OFF_QT, ws + OFF_XYZ4,
                                     (const unsigned short*)(ws + OFF_XVB),
                                     ws + OFF_IRS1, ws + OFF_IRS2,
                                     ws + OFF_ICS1, ws + OFF_THR,
                                     ws + OFF_GMA, ws + OFF_G2, ws + OFF_CS2);
    k8_res<<<1024, 256, 0, stream>>>(mot, wt, bt, ws + OFF_FLAG,
                                     ws + OFF_GMA, ws + OFF_G2, ws + OFF_CS2,
                                     ws + OFF_GN, ws + OFF_ICS1, 0);
  }

  k9_out<<<2048, 256, 0, stream>>>(ws + OFF_GMA, ws + OFF_GN, mot, gnw, gnb, pa, al,
                                   ws + OFF_FLAG, d_out);
}

// Round 2
// 299.029 us; speedup vs baseline: 1.1106x; 1.0234x over previous
//
#include <hip/hip_runtime.h>
#include <hip/hip_bf16.h>
#include <cstdio>

#define NB 2
#define NN 4096
#define NC 64
#define NQ 16
#define POS_COEF 0.1f

// ---- workspace layout (float offsets) ----
#define OFF_QT   0u            // [B][N][16] row-major q
#define OFF_QK   131072u       // [B][16][N] planar k-major q (coalesced stream)
#define OFF_XYZ4 262144u       // [B][N][4]  row-major xyz+sq
#define OFF_XYZK 294912u       // [B][4][N]  planar xyz+sq
#define OFF_IRS1 327680u       // [B][N]
#define OFF_IRS2 335872u       // [B][N]
#define OFF_THR  344064u       // [B][N]
#define OFF_ICS1 352256u       // [B][N]  1/(1e-9+cs1)
#define OFF_FLAG 360448u       // [16]
#define OFF_XVB  360464u       // [B][64][N] bf16 (262144 floats)
// --- zeroed region below ---
#define OFF_SUMS 622608u       // [B][4]
#define OFF_GN   622616u       // [2][B][8]
#define OFF_CS2  622648u       // [B][N] colsum of local
#define OFF_GMA  630840u       // [B][N][64]  G1/combined gma -> res in k8
#define OFF_G2   1155128u      // [B][N][64]  G2 (fallback path only)
#define WS_TOTAL 1679416u
#define ZERO_F   (WS_TOTAL - OFF_SUMS)
// --- optional materialized exp matrices (bf16), used iff ws_size permits ---
#define OFF_A0   1679424u      // [B][N][N] bf16 exp(corr)     (16777216 floats)
#define OFF_AE   18456640u     // [B][N][N] bf16 exp(l0)       (16777216 floats)
#define FULL_F   35233856u

using bf16x8 = __attribute__((ext_vector_type(8))) short;
using f32x4v = __attribute__((ext_vector_type(4))) float;

__device__ __forceinline__ float rcpf_(float x) { return __builtin_amdgcn_rcpf(x); }
__device__ __forceinline__ unsigned short f2bf(float x) {
  __hip_bfloat16 h = __float2bfloat16(x);
  return *(unsigned short*)&h;
}
__device__ __forceinline__ float bf2f(unsigned short u) {
  unsigned v = ((unsigned)u) << 16;
  return __builtin_bit_cast(float, v);
}

__device__ __forceinline__ float ldin(const void* p, size_t i, bool f32) {
  return f32 ? ((const float*)p)[i]
             : __bfloat162float(((const __hip_bfloat16*)p)[i]);
}

// 16-term fma tree, named float4 row against named float4 row
#define DOT16M(A0,A1,A2,A3,B0,B1,B2,B3) \
  fmaf((A0).x,(B0).x, fmaf((A0).y,(B0).y, fmaf((A0).z,(B0).z, fmaf((A0).w,(B0).w, \
  fmaf((A1).x,(B1).x, fmaf((A1).y,(B1).y, fmaf((A1).z,(B1).z, fmaf((A1).w,(B1).w, \
  fmaf((A2).x,(B2).x, fmaf((A2).y,(B2).y, fmaf((A2).z,(B2).z, fmaf((A2).w,(B2).w, \
  fmaf((A3).x,(B3).x, fmaf((A3).y,(B3).y, fmaf((A3).z,(B3).z, (A3).w*(B3).w)))))))))))))))

// dot of named row (M0..M3) against column C of k-planes k0..k15
#define DOTC(M0,M1,M2,M3,C) \
  fmaf((M0).x,k0.C, fmaf((M0).y,k1.C, fmaf((M0).z,k2.C, fmaf((M0).w,k3.C, \
  fmaf((M1).x,k4.C, fmaf((M1).y,k5.C, fmaf((M1).z,k6.C, fmaf((M1).w,k7.C, \
  fmaf((M2).x,k8.C, fmaf((M2).y,k9.C, fmaf((M2).z,k10.C, fmaf((M2).w,k11.C, \
  fmaf((M3).x,k12.C, fmaf((M3).y,k13.C, fmaf((M3).z,k14.C, (M3).w*k15.C)))))))))))))))

// planar k-plane loads: lanes read consecutive float4 -> fully coalesced
#define LKPL(base, n0) \
  const float4 k0  = *(const float4*)((base) + 0*NN  + (n0)); \
  const float4 k1  = *(const float4*)((base) + 1*NN  + (n0)); \
  const float4 k2  = *(const float4*)((base) + 2*NN  + (n0)); \
  const float4 k3  = *(const float4*)((base) + 3*NN  + (n0)); \
  const float4 k4  = *(const float4*)((base) + 4*NN  + (n0)); \
  const float4 k5  = *(const float4*)((base) + 5*NN  + (n0)); \
  const float4 k6  = *(const float4*)((base) + 6*NN  + (n0)); \
  const float4 k7  = *(const float4*)((base) + 7*NN  + (n0)); \
  const float4 k8  = *(const float4*)((base) + 8*NN  + (n0)); \
  const float4 k9  = *(const float4*)((base) + 9*NN  + (n0)); \
  const float4 k10 = *(const float4*)((base) + 10*NN + (n0)); \
  const float4 k11 = *(const float4*)((base) + 11*NN + (n0)); \
  const float4 k12 = *(const float4*)((base) + 12*NN + (n0)); \
  const float4 k13 = *(const float4*)((base) + 13*NN + (n0)); \
  const float4 k14 = *(const float4*)((base) + 14*NN + (n0)); \
  const float4 k15 = *(const float4*)((base) + 15*NN + (n0));

#define WRED(s) { s += __shfl_xor(s, 32); s += __shfl_xor(s, 16); \
  s += __shfl_xor(s, 8); s += __shfl_xor(s, 4); s += __shfl_xor(s, 2); s += __shfl_xor(s, 1); }

#define LQROW(v, base) \
  const float4 v##0 = *(const float4*)((base)); \
  const float4 v##1 = *(const float4*)((base) + 4); \
  const float4 v##2 = *(const float4*)((base) + 8); \
  const float4 v##3 = *(const float4*)((base) + 12);

// K0: detect input dtype
__global__ __launch_bounds__(256) void k0_detect(
    const unsigned short* __restrict__ ctx_u16, float* __restrict__ flag) {
  const int tid = threadIdx.x;
  int bad = 0;
  for (int i = tid; i < 8192; i += 256) {
    const unsigned short u = ctx_u16[i];
    const int e = (u >> 7) & 0xFF;
    if (e >= 134 || (e >= 1 && e <= 100)) bad++;
  }
  __shared__ int cnt;
  if (tid == 0) cnt = 0;
  __syncthreads();
  atomicAdd(&cnt, bad);
  __syncthreads();
  if (tid == 0) flag[0] = (cnt > 256) ? 1.0f : 0.0f;
}

// K1: q = Wqk @ ctx (row-major + planar), xyz (row + planar), batch sums
__global__ __launch_bounds__(256) void k1_q_xyz(
    const void* __restrict__ ctx, const void* __restrict__ xyz,
    const void* __restrict__ wqk, const float* __restrict__ flag,
    float* __restrict__ qt, float* __restrict__ qk,
    float* __restrict__ xyz4, float* __restrict__ xyzk,
    float* __restrict__ sums) {
  const bool f32 = flag[0] > 0.5f;
  const int tid = threadIdx.x;
  const int b = blockIdx.x >> 4;
  const int n = ((blockIdx.x & 15) << 8) + tid;
  __shared__ float wqT[NQ * NC];  // [c][o]
  for (int i = tid; i < NQ * NC; i += 256) {
    int o = i & 15, c = i >> 4;
    wqT[c * 16 + o] = ldin(wqk, o * 64 + c, f32);
  }
  __syncthreads();
  float4 a0 = {0,0,0,0}, a1 = {0,0,0,0}, a2 = {0,0,0,0}, a3 = {0,0,0,0};
  const size_t cbase = (size_t)b * 64 * NN + n;
#pragma unroll 4
  for (int c = 0; c < 64; ++c) {
    float x = ldin(ctx, cbase + (size_t)c * NN, f32);
    const float4 w0 = *(const float4*)(wqT + c * 16 + 0);
    const float4 w1 = *(const float4*)(wqT + c * 16 + 4);
    const float4 w2 = *(const float4*)(wqT + c * 16 + 8);
    const float4 w3 = *(const float4*)(wqT + c * 16 + 12);
    a0.x = fmaf(w0.x, x, a0.x); a0.y = fmaf(w0.y, x, a0.y); a0.z = fmaf(w0.z, x, a0.z); a0.w = fmaf(w0.w, x, a0.w);
    a1.x = fmaf(w1.x, x, a1.x); a1.y = fmaf(w1.y, x, a1.y); a1.z = fmaf(w1.z, x, a1.z); a1.w = fmaf(w1.w, x, a1.w);
    a2.x = fmaf(w2.x, x, a2.x); a2.y = fmaf(w2.y, x, a2.y); a2.z = fmaf(w2.z, x, a2.z); a2.w = fmaf(w2.w, x, a2.w);
    a3.x = fmaf(w3.x, x, a3.x); a3.y = fmaf(w3.y, x, a3.y); a3.z = fmaf(w3.z, x, a3.z); a3.w = fmaf(w3.w, x, a3.w);
  }
  float* qp = qt + (size_t)(b * NN + n) * 16;
  *(float4*)(qp + 0) = a0; *(float4*)(qp + 4) = a1;
  *(float4*)(qp + 8) = a2; *(float4*)(qp + 12) = a3;
  float* kq = qk + (size_t)b * 16 * NN + n;
  kq[0*NN]=a0.x;  kq[1*NN]=a0.y;  kq[2*NN]=a0.z;  kq[3*NN]=a0.w;
  kq[4*NN]=a1.x;  kq[5*NN]=a1.y;  kq[6*NN]=a1.z;  kq[7*NN]=a1.w;
  kq[8*NN]=a2.x;  kq[9*NN]=a2.y;  kq[10*NN]=a2.z; kq[11*NN]=a2.w;
  kq[12*NN]=a3.x; kq[13*NN]=a3.y; kq[14*NN]=a3.z; kq[15*NN]=a3.w;
  float xx = ldin(xyz, (size_t)(b * NN + n) * 3 + 0, f32);
  float yy = ldin(xyz, (size_t)(b * NN + n) * 3 + 1, f32);
  float zz = ldin(xyz, (size_t)(b * NN + n) * 3 + 2, f32);
  float4 p; p.x = xx; p.y = yy; p.z = zz; p.w = fmaf(xx, xx, fmaf(yy, yy, zz * zz));
  *(float4*)(xyz4 + (size_t)(b * NN + n) * 4) = p;
  float* kx = xyzk + (size_t)b * 4 * NN + n;
  kx[0*NN]=p.x; kx[1*NN]=p.y; kx[2*NN]=p.z; kx[3*NN]=p.w;
  float sx = p.x, sy = p.y, sz = p.z, sw = p.w;
  WRED(sx) WRED(sy) WRED(sz) WRED(sw)
  if ((tid & 63) == 0) {
    atomicAdd(&sums[b * 4 + 0], sx);
    atomicAdd(&sums[b * 4 + 1], sy);
    atomicAdd(&sums[b * 4 + 2], sz);
    atomicAdd(&sums[b * 4 + 3], sw);
  }
}

// K2: xv = Wv @ motion + bv, bf16 channel-major [b][c][n]
__global__ __launch_bounds__(256) void k2_xv(
    const void* __restrict__ mot, const void* __restrict__ wv,
    const void* __restrict__ bv, const float* __restrict__ flag,
    unsigned short* __restrict__ xvb) {
  const bool f32 = flag[0] > 0.5f;
  const int tid = threadIdx.x;
  const int b = blockIdx.x >> 6;
  const int n = ((blockIdx.x & 63) << 6) + (tid >> 2);
  const int og = tid & 3;
  __shared__ float wvT[NC * NC];
  __shared__ float bvs[NC];
  for (int i = tid; i < NC * NC; i += 256) {
    int o = i & 63, c = i >> 6;
    wvT[c * 64 + o] = ldin(wv, o * 64 + c, f32);
  }
  if (tid < 64) bvs[tid] = ldin(bv, tid, f32);
  __syncthreads();
  float4 a0 = *(const float4*)(bvs + og * 16 + 0);
  float4 a1 = *(const float4*)(bvs + og * 16 + 4);
  float4 a2 = *(const float4*)(bvs + og * 16 + 8);
  float4 a3 = *(const float4*)(bvs + og * 16 + 12);
  const size_t mbase = (size_t)b * 64 * NN + n;
#pragma unroll 4
  for (int c = 0; c < 64; ++c) {
    float x = ldin(mot, mbase + (size_t)c * NN, f32);
    const float4 w0 = *(const float4*)(wvT + c * 64 + og * 16 + 0);
    const float4 w1 = *(const float4*)(wvT + c * 64 + og * 16 + 4);
    const float4 w2 = *(const float4*)(wvT + c * 64 + og * 16 + 8);
    const float4 w3 = *(const float4*)(wvT + c * 64 + og * 16 + 12);
    a0.x = fmaf(w0.x, x, a0.x); a0.y = fmaf(w0.y, x, a0.y); a0.z = fmaf(w0.z, x, a0.z); a0.w = fmaf(w0.w, x, a0.w);
    a1.x = fmaf(w1.x, x, a1.x); a1.y = fmaf(w1.y, x, a1.y); a1.z = fmaf(w1.z, x, a1.z); a1.w = fmaf(w1.w, x, a1.w);
    a2.x = fmaf(w2.x, x, a2.x); a2.y = fmaf(w2.y, x, a2.y); a2.z = fmaf(w2.z, x, a2.z); a2.w = fmaf(w2.w, x, a2.w);
    a3.x = fmaf(w3.x, x, a3.x); a3.y = fmaf(w3.y, x, a3.y); a3.z = fmaf(w3.z, x, a3.z); a3.w = fmaf(w3.w, x, a3.w);
  }
  unsigned short* xb = xvb + (size_t)b * 64 * NN + n;
  const int o0 = og * 16;
  xb[(size_t)(o0 + 0) * NN] = f2bf(a0.x);  xb[(size_t)(o0 + 1) * NN] = f2bf(a0.y);
  xb[(size_t)(o0 + 2) * NN] = f2bf(a0.z);  xb[(size_t)(o0 + 3) * NN] = f2bf(a0.w);
  xb[(size_t)(o0 + 4) * NN] = f2bf(a1.x);  xb[(size_t)(o0 + 5) * NN] = f2bf(a1.y);
  xb[(size_t)(o0 + 6) * NN] = f2bf(a1.z);  xb[(size_t)(o0 + 7) * NN] = f2bf(a1.w);
  xb[(size_t)(o0 + 8) * NN] = f2bf(a2.x);  xb[(size_t)(o0 + 9) * NN] = f2bf(a2.y);
  xb[(size_t)(o0 +10) * NN] = f2bf(a2.z);  xb[(size_t)(o0 +11) * NN] = f2bf(a2.w);
  xb[(size_t)(o0 +12) * NN] = f2bf(a3.x);  xb[(size_t)(o0 +13) * NN] = f2bf(a3.y);
  xb[(size_t)(o0 +14) * NN] = f2bf(a3.z);  xb[(size_t)(o0 +15) * NN] = f2bf(a3.w);
}

// K2b: thr[n] = 0.1*(1e-9 + csd[n]) analytic
__global__ __launch_bounds__(256) void k2b_thr(
    const float* __restrict__ xyz4, const float* __restrict__ sums,
    float* __restrict__ thr) {
  const int idx = blockIdx.x * 256 + threadIdx.x;
  const int b = idx >> 12;
  const float4 pn = *(const float4*)(xyz4 + (size_t)idx * 4);
  const float Px = sums[b * 4 + 0], Py = sums[b * 4 + 1];
  const float Pz = sums[b * 4 + 2], S1 = sums[b * 4 + 3];
  float csd = fmaf((float)NN, pn.w, S1)
            - 2.f * (pn.x * Px + pn.y * Py + pn.z * Pz);
  thr[idx] = POS_COEF * (1e-9f + csd);
}

// ===================== fallback (round-13) p1/p3/k7 =====================

__global__ __launch_bounds__(256) void p1_rs1(
    const float* __restrict__ qt, const float* __restrict__ qk,
    float* __restrict__ irs1) {
  const int tid = threadIdx.x;
  const int b = blockIdx.x >> 8;
  const int m0 = (blockIdx.x & 255) << 4;
  const int w = tid >> 6, lane = tid & 63;
  const float* qb = qt + (size_t)b * NN * 16;
  const float* kb = qk + (size_t)b * 16 * NN;
  const int mA = m0 + w, mB = m0 + w + 4, mC = m0 + w + 8, mD = m0 + w + 12;
  LQROW(ma, qb + (size_t)mA * 16)
  LQROW(mb, qb + (size_t)mB * 16)
  LQROW(mc, qb + (size_t)mC * 16)
  LQROW(md, qb + (size_t)mD * 16)
  float sA = 0.f, sB = 0.f, sC = 0.f, sD = 0.f;
  for (int it = 0; it < 16; ++it) {
    const int n0 = (it << 8) + (lane << 2);
    LKPL(kb, n0)
    sA += __expf(fminf(DOTC(ma0,ma1,ma2,ma3,x), 80.f));
    sA += __expf(fminf(DOTC(ma0,ma1,ma2,ma3,y), 80.f));
    sA += __expf(fminf(DOTC(ma0,ma1,ma2,ma3,z), 80.f));
    sA += __expf(fminf(DOTC(ma0,ma1,ma2,ma3,w), 80.f));
    sB += __expf(fminf(DOTC(mb0,mb1,mb2,mb3,x), 80.f));
    sB += __expf(fminf(DOTC(mb0,mb1,mb2,mb3,y), 80.f));
    sB += __expf(fminf(DOTC(mb0,mb1,mb2,mb3,z), 80.f));
    sB += __expf(fminf(DOTC(mb0,mb1,mb2,mb3,w), 80.f));
    sC += __expf(fminf(DOTC(mc0,mc1,mc2,mc3,x), 80.f));
    sC += __expf(fminf(DOTC(mc0,mc1,mc2,mc3,y), 80.f));
    sC += __expf(fminf(DOTC(mc0,mc1,mc2,mc3,z), 80.f));
    sC += __expf(fminf(DOTC(mc0,mc1,mc2,mc3,w), 80.f));
    sD += __expf(fminf(DOTC(md0,md1,md2,md3,x), 80.f));
    sD += __expf(fminf(DOTC(md0,md1,md2,md3,y), 80.f));
    sD += __expf(fminf(DOTC(md0,md1,md2,md3,z), 80.f));
    sD += __expf(fminf(DOTC(md0,md1,md2,md3,w), 80.f));
  }
  WRED(sA) WRED(sB) WRED(sC) WRED(sD)
  if (lane == 0) {
    irs1[b * NN + mA] = rcpf_(sA);
    irs1[b * NN + mB] = rcpf_(sB);
    irs1[b * NN + mC] = rcpf_(sC);
    irs1[b * NN + mD] = rcpf_(sD);
  }
}

__global__ __launch_bounds__(256) void p3_rs2(
    const float* __restrict__ qt, const float* __restrict__ qk,
    const float* __restrict__ xyz4, const float* __restrict__ xyzk,
    const float* __restrict__ irs1, const float* __restrict__ ics1,
    const float* __restrict__ thr, float* __restrict__ irs2) {
  const int tid = threadIdx.x;
  const int b = blockIdx.x >> 8;
  const int m0 = (blockIdx.x & 255) << 4;
  const int w = tid >> 6, lane = tid & 63;
  const float* qb = qt + (size_t)b * NN * 16;
  const float* kb = qk + (size_t)b * 16 * NN;
  const float* xk = xyzk + (size_t)b * 4 * NN;
  const int mA = m0 + w, mB = m0 + w + 4, mC = m0 + w + 8, mD = m0 + w + 12;
  LQROW(ma, qb + (size_t)mA * 16)
  LQROW(mb, qb + (size_t)mB * 16)
  LQROW(mc, qb + (size_t)mC * 16)
  LQROW(md, qb + (size_t)mD * 16)
  const float4 pmA = *(const float4*)(xyz4 + ((size_t)b * NN + mA) * 4);
  const float4 pmB = *(const float4*)(xyz4 + ((size_t)b * NN + mB) * 4);
  const float4 pmC = *(const float4*)(xyz4 + ((size_t)b * NN + mC) * 4);
  const float4 pmD = *(const float4*)(xyz4 + ((size_t)b * NN + mD) * 4);
  const float rA = irs1[b * NN + mA];
  const float rB = irs1[b * NN + mB];
  const float rC = irs1[b * NN + mC];
  const float rD = irs1[b * NN + mD];
  float sA = 0.f, sB = 0.f, sC = 0.f, sD = 0.f;
#define P3C(S, M0,M1,M2,M3, PM, R, C) { \
    float corr_ = DOTC(M0,M1,M2,M3,C); \
    float a1v_ = __expf(fminf(corr_, 80.f)) * (R) * ic.C; \
    float dd_ = (PM).w + pw.C - 2.f * ((PM).x * px.C + (PM).y * py.C + (PM).z * pz.C); \
    dd_ = fmaxf(dd_, 0.f); \
    float l0_ = (dd_ <= th.C) ? a1v_ : 0.f; \
    S += __expf(l0_); }
  for (int it = 0; it < 16; ++it) {
    const int n0 = (it << 8) + (lane << 2);
    LKPL(kb, n0)
    const float4 px = *(const float4*)(xk + 0*NN + n0);
    const float4 py = *(const float4*)(xk + 1*NN + n0);
    const float4 pz = *(const float4*)(xk + 2*NN + n0);
    const float4 pw = *(const float4*)(xk + 3*NN + n0);
    const float4 ic = *(const float4*)(ics1 + b * NN + n0);
    const float4 th = *(const float4*)(thr + b * NN + n0);
    P3C(sA, ma0,ma1,ma2,ma3, pmA, rA, x)
    P3C(sA, ma0,ma1,ma2,ma3, pmA, rA, y)
    P3C(sA, ma0,ma1,ma2,ma3, pmA, rA, z)
    P3C(sA, ma0,ma1,ma2,ma3, pmA, rA, w)
    P3C(sB, mb0,mb1,mb2,mb3, pmB, rB, x)
    P3C(sB, mb0,mb1,mb2,mb3, pmB, rB, y)
    P3C(sB, mb0,mb1,mb2,mb3, pmB, rB, z)
    P3C(sB, mb0,mb1,mb2,mb3, pmB, rB, w)
    P3C(sC, mc0,mc1,mc2,mc3, pmC, rC, x)
    P3C(sC, mc0,mc1,mc2,mc3, pmC, rC, y)
    P3C(sC, mc0,mc1,mc2,mc3, pmC, rC, z)
    P3C(sC, mc0,mc1,mc2,mc3, pmC, rC, w)
    P3C(sD, md0,md1,md2,md3, pmD, rD, x)
    P3C(sD, md0,md1,md2,md3, pmD, rD, y)
    P3C(sD, md0,md1,md2,md3, pmD, rD, z)
    P3C(sD, md0,md1,md2,md3, pmD, rD, w)
  }
#undef P3C
  WRED(sA) WRED(sB) WRED(sC) WRED(sD)
  if (lane == 0) {
    irs2[b * NN + mA] = rcpf_(sA);
    irs2[b * NN + mB] = rcpf_(sB);
    irs2[b * NN + mC] = rcpf_(sC);
    irs2[b * NN + mD] = rcpf_(sD);
  }
}

__global__ __launch_bounds__(256) void k7_gma(
    const float* __restrict__ qt, const float* __restrict__ xyz4,
    const unsigned short* __restrict__ xvb,
    const float* __restrict__ irs1, const float* __restrict__ irs2,
    const float* __restrict__ ics1, const float* __restrict__ thr,
    float* __restrict__ g1, float* __restrict__ g2, float* __restrict__ cs2) {
  const int tid = threadIdx.x;
  const int bid = blockIdx.x;
  const int msl = bid & 7;
  const int nb = (bid >> 3) & 63;
  const int b = bid >> 9;
  const int n0 = nb << 6;
  const int mstart = msl << 9;
  __shared__ __align__(16) unsigned short attns1[64 * 72];
  __shared__ __align__(16) unsigned short attns2[64 * 72];
  __shared__ __align__(16) unsigned short xvs[64 * 72];
  const float* qb = qt + (size_t)b * NN * 16;
  const float* pb = xyz4 + (size_t)b * NN * 4;
  const int ni = tid & 63, aw = tid >> 6;
  const int na = n0 + ni;
  const float* qnp = qb + (size_t)na * 16;
  LQROW(q, qnp)
  const float4 pn = *(const float4*)(pb + (size_t)na * 4);
  const float ics1n = ics1[b * NN + na];
  const float thr_n = thr[b * NN + na];
  const int lane = tid & 63, wv = tid >> 6;
  const int lr = lane & 15, quad = lane >> 4;
  const int nw = wv << 4;
  f32x4v acc0 = {0,0,0,0}, acc1 = {0,0,0,0}, acc2 = {0,0,0,0}, acc3 = {0,0,0,0};
  f32x4v d0 = {0,0,0,0}, d1 = {0,0,0,0}, d2 = {0,0,0,0}, d3 = {0,0,0,0};
  float csacc = 0.f;
#define COMPA(MOFF, D1, D2) { \
    const int m_ = __builtin_amdgcn_readfirstlane(mw + (MOFF)); \
    const float* qm_ = qb + (size_t)m_ * 16; \
    LQROW(wq, qm_) \
    float corr_ = DOT16M(q0, q1, q2, q3, wq0, wq1, wq2, wq3); \
    const float4 pm_ = *(const float4*)(pb + (size_t)m_ * 4); \
    float a1v_ = __expf(fminf(corr_, 80.f)) * irs1[b * NN + m_] * ics1n; \
    float dd_ = pm_.w + pn.w - 2.f * (pm_.x * pn.x + pm_.y * pn.y + pm_.z * pn.z); \
    dd_ = fmaxf(dd_, 0.f); \
    float l0_ = (dd_ <= thr_n) ? a1v_ : 0.f; \
    float l2n_ = __expf(l0_) * irs2[b * NN + m_]; \
    D1 = f2bf(a1v_); D2 = f2bf(l2n_); csacc += l2n_; }
  for (int mt = 0; mt < 8; ++mt) {
    const int m0 = mstart + (mt << 6);
    __syncthreads();
    {
      const int c = tid >> 2, part = tid & 3;
      const unsigned short* src = xvb + ((size_t)b * 64 + c) * NN + m0 + part * 16;
      unsigned short* dst = xvs + c * 72 + part * 16;
      *(uint4*)dst = *(const uint4*)src;
      *(uint4*)(dst + 8) = *(const uint4*)(src + 8);
    }
    const int mw = m0 + (aw << 4);
#pragma unroll
    for (int g = 0; g < 4; ++g) {
      ushort4 u1, u2;
      COMPA(g * 4 + 0, u1.x, u2.x)
      COMPA(g * 4 + 1, u1.y, u2.y)
      COMPA(g * 4 + 2, u1.z, u2.z)
      COMPA(g * 4 + 3, u1.w, u2.w)
      *(ushort4*)(attns1 + ni * 72 + (aw << 4) + (g << 2)) = u1;
      *(ushort4*)(attns2 + ni * 72 + (aw << 4) + (g << 2)) = u2;
    }
    __syncthreads();
#pragma unroll
    for (int h = 0; h < 2; ++h) {
      const bf16x8 a1 = *(const bf16x8*)(attns1 + (nw + lr) * 72 + h * 32 + quad * 8);
      const bf16x8 a2 = *(const bf16x8*)(attns2 + (nw + lr) * 72 + h * 32 + quad * 8);
      const bf16x8 b0 = *(const bf16x8*)(xvs + (lr) * 72 + h * 32 + quad * 8);
      const bf16x8 b1 = *(const bf16x8*)(xvs + (16 + lr) * 72 + h * 32 + quad * 8);
      const bf16x8 b2 = *(const bf16x8*)(xvs + (32 + lr) * 72 + h * 32 + quad * 8);
      const bf16x8 b3 = *(const bf16x8*)(xvs + (48 + lr) * 72 + h * 32 + quad * 8);
      acc0 = __builtin_amdgcn_mfma_f32_16x16x32_bf16(a1, b0, acc0, 0, 0, 0);
      acc1 = __builtin_amdgcn_mfma_f32_16x16x32_bf16(a1, b1, acc1, 0, 0, 0);
      acc2 = __builtin_amdgcn_mfma_f32_16x16x32_bf16(a1, b2, acc2, 0, 0, 0);
      acc3 = __builtin_amdgcn_mfma_f32_16x16x32_bf16(a1, b3, acc3, 0, 0, 0);
      d0 = __builtin_amdgcn_mfma_f32_16x16x32_bf16(a2, b0, d0, 0, 0, 0);
      d1 = __builtin_amdgcn_mfma_f32_16x16x32_bf16(a2, b1, d1, 0, 0, 0);
      d2 = __builtin_amdgcn_mfma_f32_16x16x32_bf16(a2, b2, d2, 0, 0, 0);
      d3 = __builtin_amdgcn_mfma_f32_16x16x32_bf16(a2, b3, d3, 0, 0, 0);
    }
  }
#undef COMPA
  atomicAdd(&cs2[b * NN + na], csacc);
#define EPI(ACC, DST, CT) { \
    float* g_ = (DST) + ((size_t)b * NN + n0 + nw + (quad << 2)) * 64 + (CT) * 16 + lr; \
    atomicAdd(g_ + 0,   ACC[0]); \
    atomicAdd(g_ + 64,  ACC[1]); \
    atomicAdd(g_ + 128, ACC[2]); \
    atomicAdd(g_ + 192, ACC[3]); }
  EPI(acc0, g1, 0) EPI(acc1, g1, 1) EPI(acc2, g1, 2) EPI(acc3, g1, 3)
  EPI(d0, g2, 0) EPI(d1, g2, 1) EPI(d2, g2, 2) EPI(d3, g2, 3)
#undef EPI
}

// ============ materialized-exp path (used iff ws_size permits) ============

// P1W: like p1 but stores a0[m][n]=bf16(exp(corr)) and sums the ROUNDED values.
__global__ __launch_bounds__(256) void p1w_rs1(
    const float* __restrict__ qt, const float* __restrict__ qk,
    float* __restrict__ irs1, unsigned short* __restrict__ a0g) {
  const int tid = threadIdx.x;
  const int b = blockIdx.x >> 8;
  const int m0 = (blockIdx.x & 255) << 4;
  const int w = tid >> 6, lane = tid & 63;
  const float* qb = qt + (size_t)b * NN * 16;
  const float* kb = qk + (size_t)b * 16 * NN;
  unsigned short* ab = a0g + (size_t)b * NN * NN;
  const int mA = m0 + w, mB = m0 + w + 4, mC = m0 + w + 8, mD = m0 + w + 12;
  LQROW(ma, qb + (size_t)mA * 16)
  LQROW(mb, qb + (size_t)mB * 16)
  LQROW(mc, qb + (size_t)mC * 16)
  LQROW(md, qb + (size_t)mD * 16)
  float sA = 0.f, sB = 0.f, sC = 0.f, sD = 0.f;
#define P1E(S, U, UC, M0,M1,M2,M3, C) { \
    float e_ = __expf(fminf(DOTC(M0,M1,M2,M3,C), 80.f)); \
    unsigned short us_ = f2bf(e_); U.UC = us_; S += bf2f(us_); }
  for (int it = 0; it < 16; ++it) {
    const int n0 = (it << 8) + (lane << 2);
    LKPL(kb, n0)
    ushort4 uA, uB, uC, uD;
    P1E(sA, uA, x, ma0,ma1,ma2,ma3, x) P1E(sA, uA, y, ma0,ma1,ma2,ma3, y)
    P1E(sA, uA, z, ma0,ma1,ma2,ma3, z) P1E(sA, uA, w, ma0,ma1,ma2,ma3, w)
    P1E(sB, uB, x, mb0,mb1,mb2,mb3, x) P1E(sB, uB, y, mb0,mb1,mb2,mb3, y)
    P1E(sB, uB, z, mb0,mb1,mb2,mb3, z) P1E(sB, uB, w, mb0,mb1,mb2,mb3, w)
    P1E(sC, uC, x, mc0,mc1,mc2,mc3, x) P1E(sC, uC, y, mc0,mc1,mc2,mc3, y)
    P1E(sC, uC, z, mc0,mc1,mc2,mc3, z) P1E(sC, uC, w, mc0,mc1,mc2,mc3, w)
    P1E(sD, uD, x, md0,md1,md2,md3, x) P1E(sD, uD, y, md0,md1,md2,md3, y)
    P1E(sD, uD, z, md0,md1,md2,md3, z) P1E(sD, uD, w, md0,md1,md2,md3, w)
    *(ushort4*)(ab + (size_t)mA * NN + n0) = uA;
    *(ushort4*)(ab + (size_t)mB * NN + n0) = uB;
    *(ushort4*)(ab + (size_t)mC * NN + n0) = uC;
    *(ushort4*)(ab + (size_t)mD * NN + n0) = uD;
  }
#undef P1E
  WRED(sA) WRED(sB) WRED(sC) WRED(sD)
  if (lane == 0) {
    irs1[b * NN + mA] = rcpf_(sA);
    irs1[b * NN + mB] = rcpf_(sB);
    irs1[b * NN + mC] = rcpf_(sC);
    irs1[b * NN + mD] = rcpf_(sD);
  }
}

// P2R: cs1 via SYMMETRY of corr: cs1[n] = sum_m a0[n][m]*irs1[m].
__global__ __launch_bounds__(256) void p2r_cs1(
    const unsigned short* __restrict__ a0g, const float* __restrict__ irs1,
    float* __restrict__ ics1) {
  const int tid = threadIdx.x;
  const int w = tid >> 6, l = tid & 63;
  const int bi = blockIdx.x;                 // 0..2047
  const int b = bi >> 10;
  const int n = ((bi & 1023) << 2) + w;      // 4 rows per block, 1 per wave
  const unsigned short* row = a0g + ((size_t)b * NN + n) * NN;
  const float* ir = irs1 + b * NN;
  float s = 0.f;
#pragma unroll
  for (int it = 0; it < 8; ++it) {
    const int m = (it << 9) + (l << 3);
    const uint4 u = *(const uint4*)(row + m);
    const float4 i0 = *(const float4*)(ir + m);
    const float4 i1 = *(const float4*)(ir + m + 4);
    s = fmaf(bf2f((unsigned short)(u.x & 0xffffu)), i0.x, s);
    s = fmaf(bf2f((unsigned short)(u.x >> 16)),     i0.y, s);
    s = fmaf(bf2f((unsigned short)(u.y & 0xffffu)), i0.z, s);
    s = fmaf(bf2f((unsigned short)(u.y >> 16)),     i0.w, s);
    s = fmaf(bf2f((unsigned short)(u.z & 0xffffu)), i1.x, s);
    s = fmaf(bf2f((unsigned short)(u.z >> 16)),     i1.y, s);
    s = fmaf(bf2f((unsigned short)(u.w & 0xffffu)), i1.z, s);
    s = fmaf(bf2f((unsigned short)(u.w >> 16)),     i1.w, s);
  }
  WRED(s)
  if (l == 0) ics1[b * NN + n] = rcpf_(1e-9f + s);
}

// P3W: reads a0 rows (no corr recompute), stores ae[m][n]=bf16(exp(l0)),
// sums ROUNDED values for irs2.
__global__ __launch_bounds__(256) void p3w_rs2(
    const float* __restrict__ xyz4, const float* __restrict__ xyzk,
    const float* __restrict__ irs1, const float* __restrict__ ics1,
    const float* __restrict__ thr, float* __restrict__ irs2,
    const unsigned short* __restrict__ a0g, unsigned short* __restrict__ aeg) {
  const int tid = threadIdx.x;
  const int b = blockIdx.x >> 8;
  const int m0 = (blockIdx.x & 255) << 4;
  const int w = tid >> 6, lane = tid & 63;
  const float* xk = xyzk + (size_t)b * 4 * NN;
  const unsigned short* ab = a0g + (size_t)b * NN * NN;
  unsigned short* eb = aeg + (size_t)b * NN * NN;
  const int mA = m0 + w, mB = m0 + w + 4, mC = m0 + w + 8, mD = m0 + w + 12;
  const float4 pmA = *(const float4*)(xyz4 + ((size_t)b * NN + mA) * 4);
  const float4 pmB = *(const float4*)(xyz4 + ((size_t)b * NN + mB) * 4);
  const float4 pmC = *(const float4*)(xyz4 + ((size_t)b * NN + mC) * 4);
  const float4 pmD = *(const float4*)(xyz4 + ((size_t)b * NN + mD) * 4);
  const float rA = irs1[b * NN + mA];
  const float rB = irs1[b * NN + mB];
  const float rC = irs1[b * NN + mC];
  const float rD = irs1[b * NN + mD];
  float sA = 0.f, sB = 0.f, sC = 0.f, sD = 0.f;
#define P3W(S, RU, EU, UC, PM, R, C) { \
    float a1v_ = bf2f(RU.UC) * (R) * ic.C; \
    float dd_ = (PM).w + pw.C - 2.f * ((PM).x * px.C + (PM).y * py.C + (PM).z * pz.C); \
    dd_ = fmaxf(dd_, 0.f); \
    float l0_ = (dd_ <= th.C) ? a1v_ : 0.f; \
    unsigned short us_ = f2bf(__expf(l0_)); EU.UC = us_; S += bf2f(us_); }
  for (int it = 0; it < 16; ++it) {
    const int n0 = (it << 8) + (lane << 2);
    const float4 px = *(const float4*)(xk + 0*NN + n0);
    const float4 py = *(const float4*)(xk + 1*NN + n0);
    const float4 pz = *(const float4*)(xk + 2*NN + n0);
    const float4 pw = *(const float4*)(xk + 3*NN + n0);
    const float4 ic = *(const float4*)(ics1 + b * NN + n0);
    const float4 th = *(const float4*)(thr + b * NN + n0);
    const ushort4 rA4 = *(const ushort4*)(ab + (size_t)mA * NN + n0);
    const ushort4 rB4 = *(const ushort4*)(ab + (size_t)mB * NN + n0);
    const ushort4 rC4 = *(const ushort4*)(ab + (size_t)mC * NN + n0);
    const ushort4 rD4 = *(const ushort4*)(ab + (size_t)mD * NN + n0);
    ushort4 eA, eB, eC, eD;
    P3W(sA, rA4, eA, x, pmA, rA, x) P3W(sA, rA4, eA, y, pmA, rA, y)
    P3W(sA, rA4, eA, z, pmA, rA, z) P3W(sA, rA4, eA, w, pmA, rA, w)
    P3W(sB, rB4, eB, x, pmB, rB, x) P3W(sB, rB4, eB, y, pmB, rB, y)
    P3W(sB, rB4, eB, z, pmB, rB, z) P3W(sB, rB4, eB, w, pmB, rB, w)
    P3W(sC, rC4, eC, x, pmC, rC, x) P3W(sC, rC4, eC, y, pmC, rC, y)
    P3W(sC, rC4, eC, z, pmC, rC, z) P3W(sC, rC4, eC, w, pmC, rC, w)
    P3W(sD, rD4, eD, x, pmD, rD, x) P3W(sD, rD4, eD, y, pmD, rD, y)
    P3W(sD, rD4, eD, z, pmD, rD, z) P3W(sD, rD4, eD, w, pmD, rD, w)
    *(ushort4*)(eb + (size_t)mA * NN + n0) = eA;
    *(ushort4*)(eb + (size_t)mB * NN + n0) = eB;
    *(ushort4*)(eb + (size_t)mC * NN + n0) = eC;
    *(ushort4*)(eb + (size_t)mD * NN + n0) = eD;
  }
#undef P3W
  WRED(sA) WRED(sB) WRED(sC) WRED(sD)
  if (lane == 0) {
    irs2[b * NN + mA] = rcpf_(sA);
    irs2[b * NN + mB] = rcpf_(sB);
    irs2[b * NN + mC] = rcpf_(sC);
    irs2[b * NN + mD] = rcpf_(sD);
  }
}

// P4: cs2[n] = sum_m bf16(bf16(ae[m][n]) * irs2[m])  -- exact match of the
// values k7n stages into the MFMA.  Coalesced column reduction over ae.
__global__ __launch_bounds__(256) void p4_cs2(
    const unsigned short* __restrict__ aeg, const float* __restrict__ irs2,
    float* __restrict__ cs2) {
  const int tid = threadIdx.x;
  const int bid = blockIdx.x;              // B*8*16 = 256 blocks
  const int ms = bid & 15;                 // m strip (256 rows)
  const int ng = (bid >> 4) & 7;           // n group (512 cols)
  const int b  = bid >> 7;
  const int n2 = (ng << 9) + (tid << 1);   // 2 columns per thread
  const unsigned short* eb = aeg + (size_t)b * NN * NN + n2;
  const float* r2 = irs2 + b * NN;
  float s0 = 0.f, s1 = 0.f;
  const int m0 = ms << 8;
#pragma unroll 4
  for (int m = m0; m < m0 + 256; ++m) {
    const unsigned u = *(const unsigned*)(eb + (size_t)m * NN);
    const float r = r2[m];
    s0 += bf2f(f2bf(bf2f((unsigned short)(u & 0xffffu)) * r));
    s1 += bf2f(f2bf(bf2f((unsigned short)(u >> 16)) * r));
  }
  atomicAdd(&cs2[b * NN + n2], s0);
  atomicAdd(&cs2[b * NN + n2 + 1], s1);
}

// LDS swizzle: spreads both the b32 transpose-writes (2-way, free) and the
// b128 reads (uniform) across banks.  row&7 -> byte bits 4-6, row bits 3-4
// -> byte bits 5-6.
#define SW(r) ((((r) & 7) << 4) ^ ((((r) >> 3) & 3) << 5))

// K7N: GMA with fused g1/g2 combine (needs cs2 from p4).
//  - double-buffered LDS, ONE barrier per tile, prefetch distance 2
//  - per-block m-strip 1024 (msl=4): atomics 4x fewer than msl=8, and the
//    combined epilogue emits ONE output matrix (16 atomics/thread total)
//  - corrected swizzle: phase-A b32 LDS writes now 2-way (free)
__global__ __launch_bounds__(256) void k7n_gma(
    const unsigned short* __restrict__ a0g, const unsigned short* __restrict__ aeg,
    const unsigned short* __restrict__ xvb,
    const float* __restrict__ irs1, const float* __restrict__ irs2,
    const float* __restrict__ ics1, const float* __restrict__ cs2,
    float* __restrict__ gma) {
  const int tid = threadIdx.x;
  const int bid = blockIdx.x;              // 512 blocks: B * 64 nb * 4 msl
  const int msl = bid & 3;
  const int nb  = (bid >> 2) & 63;
  const int b   = bid >> 8;
  const int n0 = nb << 6;
  const int mstart = msl << 10;            // 1024-row m strip -> 16 tiles
  __shared__ __align__(16) unsigned short attns1[2][64 * 64];
  __shared__ __align__(16) unsigned short attns2[2][64 * 64];
  __shared__ __align__(16) unsigned short xvs[2][64 * 64];
  const unsigned short* ab = a0g + (size_t)b * NN * NN;
  const unsigned short* ebp = aeg + (size_t)b * NN * NN;
  const float* irs1b = irs1 + b * NN;
  const float* irs2b = irs2 + b * NN;
  const int w = tid >> 6, l = tid & 63;
  // phase-A a-load mapping: wave w stages m-rows w*16..w*16+15; lane covers
  // an even/odd row pair x 8 n-columns
  const int lrow0 = (w << 4) + ((l >> 3) << 1);
  const int nc8 = (l & 7) << 3;
  const int gcol = n0 + nc8;
  // xv staging mapping (row = channel, col = m)
  const int xc = tid >> 2, xpart = tid & 3;
  const unsigned short* xvp = xvb + ((size_t)b * 64 + xc) * NN;
  // phase-B mapping
  const int lr = l & 15, quad = l >> 4;
  const int nw = w << 4;
  f32x4v acc0 = {0,0,0,0}, acc1 = {0,0,0,0}, acc2 = {0,0,0,0}, acc3 = {0,0,0,0};
  f32x4v d0 = {0,0,0,0}, d1 = {0,0,0,0}, d2 = {0,0,0,0}, d3 = {0,0,0,0};

  uint4 pa0A, pa1A, pe0A, pe1A, pv0A, pv1A;
  uint4 pa0B, pa1B, pe0B, pe1B, pv0B, pv1B;
  float r1aA, r1bA, r2aA, r2bA, r1aB, r1bB, r2aB, r2bB;

#define ISSUE(S, MT) { \
    const int m0_ = mstart + ((MT) << 6); \
    const size_t ra_ = (size_t)(m0_ + lrow0) * NN + gcol; \
    pa0##S = *(const uint4*)(ab + ra_); \
    pa1##S = *(const uint4*)(ab + ra_ + NN); \
    pe0##S = *(const uint4*)(ebp + ra_); \
    pe1##S = *(const uint4*)(ebp + ra_ + NN); \
    pv0##S = *(const uint4*)(xvp + m0_ + (xpart << 4)); \
    pv1##S = *(const uint4*)(xvp + m0_ + (xpart << 4) + 8); \
    r1a##S = irs1b[m0_ + lrow0]; r1b##S = irs1b[m0_ + lrow0 + 1]; \
    r2a##S = irs2b[m0_ + lrow0]; r2b##S = irs2b[m0_ + lrow0 + 1]; }

#define CVW(D0, D1, SH, J, R0, R1, ARR) { \
    const float v0_ = bf2f((unsigned short)(((D0) >> (SH)) & 0xffffu)) * (R0); \
    const float v1_ = bf2f((unsigned short)(((D1) >> (SH)) & 0xffffu)) * (R1); \
    const unsigned pk_ = (unsigned)f2bf(v0_) | ((unsigned)f2bf(v1_) << 16); \
    const int nl_ = nc8 + (J); \
    *(unsigned*)((char*)(ARR) + ((((nl_) << 7) + (lrow0 << 1)) ^ SW(nl_))) = pk_; }

#define WR8(U0, U1, R0, R1, ARR) \
    CVW(U0.x, U1.x, 0,  0, R0, R1, ARR) CVW(U0.x, U1.x, 16, 1, R0, R1, ARR) \
    CVW(U0.y, U1.y, 0,  2, R0, R1, ARR) CVW(U0.y, U1.y, 16, 3, R0, R1, ARR) \
    CVW(U0.z, U1.z, 0,  4, R0, R1, ARR) CVW(U0.z, U1.z, 16, 5, R0, R1, ARR) \
    CVW(U0.w, U1.w, 0,  6, R0, R1, ARR) CVW(U0.w, U1.w, 16, 7, R0, R1, ARR)

#define STX(XARR, PV0, PV1) { \
    const int xb_ = (xc << 7) + (xpart << 5); \
    *(uint4*)((char*)(XARR) + ((xb_) ^ SW(xc))) = PV0; \
    *(uint4*)((char*)(XARR) + ((xb_ + 16) ^ SW(xc))) = PV1; }

#define LDSW(ARR, ROW, H, Q) \
    (*(const bf16x8*)((const char*)(ARR) + \
      ((((ROW) << 7) + ((H) << 6) + ((Q) << 4)) ^ SW(ROW))))

#define MPH(A1P, A2P, XVP_) { \
    for (int h = 0; h < 2; ++h) { \
      const bf16x8 fa1 = LDSW(A1P, nw + lr, h, quad); \
      const bf16x8 fa2 = LDSW(A2P, nw + lr, h, quad); \
      const bf16x8 fb0 = LDSW(XVP_, lr, h, quad); \
      const bf16x8 fb1 = LDSW(XVP_, 16 + lr, h, quad); \
      const bf16x8 fb2 = LDSW(XVP_, 32 + lr, h, quad); \
      const bf16x8 fb3 = LDSW(XVP_, 48 + lr, h, quad); \
      acc0 = __builtin_amdgcn_mfma_f32_16x16x32_bf16(fa1, fb0, acc0, 0, 0, 0); \
      acc1 = __builtin_amdgcn_mfma_f32_16x16x32_bf16(fa1, fb1, acc1, 0, 0, 0); \
      acc2 = __builtin_amdgcn_mfma_f32_16x16x32_bf16(fa1, fb2, acc2, 0, 0, 0); \
      acc3 = __builtin_amdgcn_mfma_f32_16x16x32_bf16(fa1, fb3, acc3, 0, 0, 0); \
      d0 = __builtin_amdgcn_mfma_f32_16x16x32_bf16(fa2, fb0, d0, 0, 0, 0); \
      d1 = __builtin_amdgcn_mfma_f32_16x16x32_bf16(fa2, fb1, d1, 0, 0, 0); \
      d2 = __builtin_amdgcn_mfma_f32_16x16x32_bf16(fa2, fb2, d2, 0, 0, 0); \
      d3 = __builtin_amdgcn_mfma_f32_16x16x32_bf16(fa2, fb3, d3, 0, 0, 0); \
    } }

  ISSUE(A, 0)
  ISSUE(B, 1)
  for (int mt = 0; mt < 16; mt += 2) {
    WR8(pa0A, pa1A, r1aA, r1bA, attns1[0])
    WR8(pe0A, pe1A, r2aA, r2bA, attns2[0])
    STX(xvs[0], pv0A, pv1A)
    __syncthreads();
    if (mt + 2 < 16) { ISSUE(A, mt + 2) }
    MPH(attns1[0], attns2[0], xvs[0])
    WR8(pa0B, pa1B, r1aB, r1bB, attns1[1])
    WR8(pe0B, pe1B, r2aB, r2bB, attns2[1])
    STX(xvs[1], pv0B, pv1B)
    __syncthreads();
    if (mt + 3 < 16) { ISSUE(B, mt + 3) }
    MPH(attns1[1], attns2[1], xvs[1])
  }
#undef ISSUE
#undef CVW
#undef WR8
#undef STX
#undef LDSW
#undef MPH
  // combined epilogue: gma[n][c] += acc*ics1[n] + d*ics2[n]
  float w10, w11, w12, w13, w20, w21, w22, w23;
  {
    const int nr = n0 + nw + (quad << 2);
    w10 = ics1[b * NN + nr + 0]; w20 = rcpf_(1e-9f + cs2[b * NN + nr + 0]);
    w11 = ics1[b * NN + nr + 1]; w21 = rcpf_(1e-9f + cs2[b * NN + nr + 1]);
    w12 = ics1[b * NN + nr + 2]; w22 = rcpf_(1e-9f + cs2[b * NN + nr + 2]);
    w13 = ics1[b * NN + nr + 3]; w23 = rcpf_(1e-9f + cs2[b * NN + nr + 3]);
  }
#define EPI(ACC, DD, CT) { \
    float* g_ = gma + ((size_t)b * NN + n0 + nw + (quad << 2)) * 64 + (CT) * 16 + lr; \
    atomicAdd(g_ + 0,   fmaf(ACC[0], w10, DD[0] * w20)); \
    atomicAdd(g_ + 64,  fmaf(ACC[1], w11, DD[1] * w21)); \
    atomicAdd(g_ + 128, fmaf(ACC[2], w12, DD[2] * w22)); \
    atomicAdd(g_ + 192, fmaf(ACC[3], w13, DD[3] * w23)); }
  EPI(acc0, d0, 0) EPI(acc1, d1, 1) EPI(acc2, d2, 2) EPI(acc3, d3, 3)
#undef EPI
}

// ===================== common p2 / k8 / k9 =====================

__global__ __launch_bounds__(256) void p2_cs1(
    const float* __restrict__ qt, const float* __restrict__ qk,
    const float* __restrict__ irs1, float* __restrict__ ics1) {
  const int tid = threadIdx.x;
  const int b = blockIdx.x >> 8;
  const int n0t = (blockIdx.x & 255) << 4;
  const int w = tid >> 6, lane = tid & 63;
  const float* qb = qt + (size_t)b * NN * 16;
  const float* kb = qk + (size_t)b * 16 * NN;
  const int nA = n0t + w, nB = n0t + w + 4, nC = n0t + w + 8, nD = n0t + w + 12;
  LQROW(na, qb + (size_t)nA * 16)
  LQROW(nb, qb + (size_t)nB * 16)
  LQROW(nc, qb + (size_t)nC * 16)
  LQROW(nd, qb + (size_t)nD * 16)
  float sA = 0.f, sB = 0.f, sC = 0.f, sD = 0.f;
  for (int it = 0; it < 16; ++it) {
    const int m0 = (it << 8) + (lane << 2);
    LKPL(kb, m0)
    const float4 r1 = *(const float4*)(irs1 + b * NN + m0);
    sA = fmaf(__expf(fminf(DOTC(na0,na1,na2,na3,x), 80.f)), r1.x, sA);
    sA = fmaf(__expf(fminf(DOTC(na0,na1,na2,na3,y), 80.f)), r1.y, sA);
    sA = fmaf(__expf(fminf(DOTC(na0,na1,na2,na3,z), 80.f)), r1.z, sA);
    sA = fmaf(__expf(fminf(DOTC(na0,na1,na2,na3,w), 80.f)), r1.w, sA);
    sB = fmaf(__expf(fminf(DOTC(nb0,nb1,nb2,nb3,x), 80.f)), r1.x, sB);
    sB = fmaf(__expf(fminf(DOTC(nb0,nb1,nb2,nb3,y), 80.f)), r1.y, sB);
    sB = fmaf(__expf(fminf(DOTC(nb0,nb1,nb2,nb3,z), 80.f)), r1.z, sB);
    sB = fmaf(__expf(fminf(DOTC(nb0,nb1,nb2,nb3,w), 80.f)), r1.w, sB);
    sC = fmaf(__expf(fminf(DOTC(nc0,nc1,nc2,nc3,x), 80.f)), r1.x, sC);
    sC = fmaf(__expf(fminf(DOTC(nc0,nc1,nc2,nc3,y), 80.f)), r1.y, sC);
    sC = fmaf(__expf(fminf(DOTC(nc0,nc1,nc2,nc3,z), 80.f)), r1.z, sC);
    sC = fmaf(__expf(fminf(DOTC(nc0,nc1,nc2,nc3,w), 80.f)), r1.w, sC);
    sD = fmaf(__expf(fminf(DOTC(nd0,nd1,nd2,nd3,x), 80.f)), r1.x, sD);
    sD = fmaf(__expf(fminf(DOTC(nd0,nd1,nd2,nd3,y), 80.f)), r1.y, sD);
    sD = fmaf(__expf(fminf(DOTC(nd0,nd1,nd2,nd3,z), 80.f)), r1.z, sD);
    sD = fmaf(__expf(fminf(DOTC(nd0,nd1,nd2,nd3,w), 80.f)), r1.w, sD);
  }
  WRED(sA) WRED(sB) WRED(sC) WRED(sD)
  if (lane == 0) {
    ics1[b * NN + nA] = rcpf_(1e-9f + sA);
    ics1[b * NN + nB] = rcpf_(1e-9f + sB);
    ics1[b * NN + nC] = rcpf_(1e-9f + sC);
    ics1[b * NN + nD] = rcpf_(1e-9f + sD);
  }
}

// mode 0: gma = g1 + g2*ics2 (fallback);  mode 2: gma already combined in g1.
__global__ __launch_bounds__(256) void k8_res(
    const void* __restrict__ mot, const void* __restrict__ wt,
    const void* __restrict__ bt, const float* __restrict__ flag,
    float* __restrict__ g1_res, const float* __restrict__ g2,
    const float* __restrict__ cs2, float* __restrict__ gn,
    const float* __restrict__ ics1, int g1mode) {
  const bool f32 = flag[0] > 0.5f;
  const int tid = threadIdx.x;
  const int bid = blockIdx.x;
  const int b = bid >> 9;
  const int n0 = (bid & 511) << 3;
  __shared__ float wtT[64 * 65];
  __shared__ float bts[64];
  __shared__ float md[8 * 64];
  __shared__ float gs[8], gss[8];
  for (int i = tid; i < 4096; i += 256) {
    int o = i & 63, c = i >> 6;
    wtT[c * 65 + o] = ldin(wt, o * 64 + c, f32);
  }
  if (tid < 64) bts[tid] = ldin(bt, tid, f32);
  if (tid < 8) { gs[tid] = 0.f; gss[tid] = 0.f; }
#pragma unroll
  for (int r = 0; r < 2; ++r) {
    const int idx = tid * 2 + r;
    const int c = idx & 63, nl = idx >> 6;
    const size_t gi = ((size_t)b * NN + n0 + nl) * 64 + c;
    float gmav;
    if (g1mode == 2) {
      gmav = g1_res[gi];
    } else {
      const float ics2n = rcpf_(1e-9f + cs2[b * NN + n0 + nl]);
      float g1v = g1_res[gi];
      if (g1mode == 1) g1v *= ics1[b * NN + n0 + nl];
      gmav = fmaf(g2[gi], ics2n, g1v);
    }
    md[nl * 64 + c] = ldin(mot, ((size_t)b * 64 + c) * NN + n0 + nl, f32) - gmav;
  }
  __syncthreads();
  const int o = tid & 63, ng = tid >> 6;
  const int nl0 = ng * 2, nl1 = ng * 2 + 1;
  float a0 = bts[o], a1 = bts[o];
#pragma unroll 8
  for (int c = 0; c < 64; ++c) {
    float w = wtT[c * 65 + o];
    a0 = fmaf(w, md[nl0 * 64 + c], a0);
    a1 = fmaf(w, md[nl1 * 64 + c], a1);
  }
  g1_res[((size_t)b * NN + n0 + nl0) * 64 + o] = a0;
  g1_res[((size_t)b * NN + n0 + nl1) * 64 + o] = a1;
  atomicAdd(&gs[o >> 3], a0 + a1);
  atomicAdd(&gss[o >> 3], a0 * a0 + a1 * a1);
  __syncthreads();
  if (tid < 8) atomicAdd(&gn[b * 8 + tid], gs[tid]);
  else if (tid < 16) atomicAdd(&gn[16 + b * 8 + (tid - 8)], gss[tid - 8]);
}

__global__ __launch_bounds__(256) void k9_out(
    const float* __restrict__ res, const float* __restrict__ gn,
    const void* __restrict__ mot,
    const void* __restrict__ gnw, const void* __restrict__ gnb,
    const void* __restrict__ pa, const void* __restrict__ al,
    const float* __restrict__ flag, void* __restrict__ out) {
  const bool f32 = flag[0] > 0.5f;
  const int idx = blockIdx.x * 256 + threadIdx.x;
  const int n = idx & 4095;
  const int c = (idx >> 12) & 63;
  const int b = idx >> 18;
  const int g = c >> 3;
  const float inv_cnt = 1.f / 32768.f;
  float mean = gn[b * 8 + g] * inv_cnt;
  float var = gn[16 + b * 8 + g] * inv_cnt - mean * mean;
  var = fmaxf(var, 0.f);
  float rstd = rsqrtf(var + 1e-5f);
  float r = res[((size_t)b * NN + n) * 64 + c];
  float y = (r - mean) * rstd * ldin(gnw, c, f32) + ldin(gnb, c, f32);
  float slope = ldin(pa, 0, f32);
  y = (y >= 0.f) ? y : slope * y;
  float o = ldin(al, 0, f32) * y + ldin(mot, idx, f32);
  if (f32) ((float*)out)[idx] = o;
  else     ((__hip_bfloat16*)out)[idx] = __float2bfloat16(o);
}

extern "C" void kernel_launch(void* const* d_in, const int* in_sizes, int n_in,
                              void* d_out, int out_size, void* d_ws, size_t ws_size,
                              hipStream_t stream) {
  const void* ctx = d_in[0];
  const void* mot = d_in[1];
  const void* xyz = d_in[2];
  const void* wqk = d_in[3];
  const void* wv  = d_in[4];
  const void* bv  = d_in[5];
  const void* wt  = d_in[6];
  const void* bt  = d_in[7];
  const void* gnw = d_in[8];
  const void* gnb = d_in[9];
  const void* pa  = d_in[10];
  const void* al  = d_in[11];
  float* ws = (float*)d_ws;
  const bool big = ws_size >= (size_t)FULL_F * sizeof(float);

  if (ws_size < (size_t)WS_TOTAL * sizeof(float))
    fprintf(stderr, "[gma3d] WARNING ws_size=%zu < needed %zu\n",
            ws_size, (size_t)WS_TOTAL * sizeof(float));

  hipMemsetAsync(ws + OFF_SUMS, 0, (size_t)ZERO_F * sizeof(float), stream);

  k0_detect<<<1, 256, 0, stream>>>((const unsigned short*)ctx, ws + OFF_FLAG);
  k1_q_xyz<<<32, 256, 0, stream>>>(ctx, xyz, wqk, ws + OFF_FLAG,
                                   ws + OFF_QT, ws + OFF_QK,
                                   ws + OFF_XYZ4, ws + OFF_XYZK, ws + OFF_SUMS);
  k2_xv<<<128, 256, 0, stream>>>(mot, wv, bv, ws + OFF_FLAG,
                                 (unsigned short*)(ws + OFF_XVB));
  k2b_thr<<<32, 256, 0, stream>>>(ws + OFF_XYZ4, ws + OFF_SUMS, ws + OFF_THR);

  if (big) {
    unsigned short* a0 = (unsigned short*)(ws + OFF_A0);
    unsigned short* ae = (unsigned short*)(ws + OFF_AE);
    p1w_rs1<<<512, 256, 0, stream>>>(ws + OFF_QT, ws + OFF_QK, ws + OFF_IRS1, a0);
    p2r_cs1<<<2048, 256, 0, stream>>>(a0, ws + OFF_IRS1, ws + OFF_ICS1);
    p3w_rs2<<<512, 256, 0, stream>>>(ws + OFF_XYZ4, ws + OFF_XYZK,
                                     ws + OFF_IRS1, ws + OFF_ICS1, ws + OFF_THR,
                                     ws + OFF_IRS2, a0, ae);
    p4_cs2<<<256, 256, 0, stream>>>(ae, ws + OFF_IRS2, ws + OFF_CS2);
    k7n_gma<<<512, 256, 0, stream>>>(a0, ae,
                                     (const unsigned short*)(ws + OFF_XVB),
                                     ws + OFF_IRS1, ws + OFF_IRS2,
                                     ws + OFF_ICS1, ws + OFF_CS2,
                                     ws + OFF_GMA);
    k8_res<<<1024, 256, 0, stream>>>(mot, wt, bt, ws + OFF_FLAG,
                                     ws + OFF_GMA, ws + OFF_G2, ws + OFF_CS2,
                                     ws + OFF_GN, ws + OFF_ICS1, 2);
  } else {
    p1_rs1<<<512, 256, 0, stream>>>(ws + OFF_QT, ws + OFF_QK, ws + OFF_IRS1);
    p2_cs1<<<512, 256, 0, stream>>>(ws + OFF_QT, ws + OFF_QK, ws + OFF_IRS1, ws + OFF_ICS1);
    p3_rs2<<<512, 256, 0, stream>>>(ws + OFF_QT, ws + OFF_QK,
                                    ws + OFF_XYZ4, ws + OFF_XYZK,
                                    ws + OFF_IRS1, ws + OFF_ICS1, ws + OFF_THR,
                                    ws + OFF_IRS2);
    k7_gma<<<1024, 256, 0, stream>>>(ws + OFF_QT, ws + OFF_XYZ4,
                                     (const unsigned short*)(ws + OFF_XVB),
                                     ws + OFF_IRS1, ws + OFF_IRS2,
                                     ws + OFF_ICS1, ws + OFF_THR,
                                     ws + OFF_GMA, ws + OFF_G2, ws + OFF_CS2);
    k8_res<<<1024, 256, 0, stream>>>(mot, wt, bt, ws + OFF_FLAG,
                                     ws + OFF_GMA, ws + OFF_G2, ws + OFF_CS2,
                                     ws + OFF_GN, ws + OFF_ICS1, 0);
  }

  k9_out<<<2048, 256, 0, stream>>>(ws + OFF_GMA, ws + OFF_GN, mot, gnw, gnb, pa, al,
                                   ws + OFF_FLAG, d_out);
}

// Round 3
// 283.696 us; speedup vs baseline: 1.1706x; 1.0540x over previous
//
#include <hip/hip_runtime.h>
#include <hip/hip_bf16.h>
#include <cstdio>

#define NB 2
#define NN 4096
#define NC 64
#define NQ 16
#define POS_COEF 0.1f

// ---- workspace layout (float offsets) ----
#define OFF_QT   0u            // [B][N][16] row-major q
#define OFF_QK   131072u       // [B][16][N] planar k-major q (coalesced stream)
#define OFF_XYZ4 262144u       // [B][N][4]  row-major xyz+sq
#define OFF_XYZK 294912u       // [B][4][N]  planar xyz+sq
#define OFF_IRS1 327680u       // [B][N]
#define OFF_IRS2 335872u       // [B][N]
#define OFF_THR  344064u       // [B][N]
#define OFF_ICS1 352256u       // [B][N]  1/(1e-9+cs1)
#define OFF_FLAG 360448u       // [16]
#define OFF_XVB  360464u       // [B][64][N] bf16 (262144 floats)
// --- zeroed region below ---
#define OFF_SUMS 622608u       // [B][4]
#define OFF_GN   622616u       // [2][B][8]
#define OFF_CS2  622648u       // [B][N] colsum of local
#define OFF_GMA  630840u       // [B][N][64]  G1/combined gma -> res in k8
#define OFF_G2   1155128u      // [B][N][64]  G2 (fallback path only)
#define WS_TOTAL 1679416u
#define ZERO_F   (WS_TOTAL - OFF_SUMS)
// --- optional materialized exp matrices (bf16), used iff ws_size permits ---
#define OFF_A0   1679424u      // [B][N][N] bf16 exp(corr)     (16777216 floats)
#define OFF_AE   18456640u     // [B][N][N] bf16 exp(l0)       (16777216 floats)
#define FULL_F   35233856u

using bf16x8 = __attribute__((ext_vector_type(8))) short;
using f32x4v = __attribute__((ext_vector_type(4))) float;

__device__ __forceinline__ float rcpf_(float x) { return __builtin_amdgcn_rcpf(x); }
__device__ __forceinline__ unsigned short f2bf(float x) {
  __hip_bfloat16 h = __float2bfloat16(x);
  return *(unsigned short*)&h;
}
__device__ __forceinline__ float bf2f(unsigned short u) {
  unsigned v = ((unsigned)u) << 16;
  return __builtin_bit_cast(float, v);
}

__device__ __forceinline__ float ldin(const void* p, size_t i, bool f32) {
  return f32 ? ((const float*)p)[i]
             : __bfloat162float(((const __hip_bfloat16*)p)[i]);
}

// 16-term fma tree, named float4 row against named float4 row
#define DOT16M(A0,A1,A2,A3,B0,B1,B2,B3) \
  fmaf((A0).x,(B0).x, fmaf((A0).y,(B0).y, fmaf((A0).z,(B0).z, fmaf((A0).w,(B0).w, \
  fmaf((A1).x,(B1).x, fmaf((A1).y,(B1).y, fmaf((A1).z,(B1).z, fmaf((A1).w,(B1).w, \
  fmaf((A2).x,(B2).x, fmaf((A2).y,(B2).y, fmaf((A2).z,(B2).z, fmaf((A2).w,(B2).w, \
  fmaf((A3).x,(B3).x, fmaf((A3).y,(B3).y, fmaf((A3).z,(B3).z, (A3).w*(B3).w)))))))))))))))

// dot of named row (M0..M3) against column C of k-planes k0..k15
#define DOTC(M0,M1,M2,M3,C) \
  fmaf((M0).x,k0.C, fmaf((M0).y,k1.C, fmaf((M0).z,k2.C, fmaf((M0).w,k3.C, \
  fmaf((M1).x,k4.C, fmaf((M1).y,k5.C, fmaf((M1).z,k6.C, fmaf((M1).w,k7.C, \
  fmaf((M2).x,k8.C, fmaf((M2).y,k9.C, fmaf((M2).z,k10.C, fmaf((M2).w,k11.C, \
  fmaf((M3).x,k12.C, fmaf((M3).y,k13.C, fmaf((M3).z,k14.C, (M3).w*k15.C)))))))))))))))

// planar k-plane loads: lanes read consecutive float4 -> fully coalesced
#define LKPL(base, n0) \
  const float4 k0  = *(const float4*)((base) + 0*NN  + (n0)); \
  const float4 k1  = *(const float4*)((base) + 1*NN  + (n0)); \
  const float4 k2  = *(const float4*)((base) + 2*NN  + (n0)); \
  const float4 k3  = *(const float4*)((base) + 3*NN  + (n0)); \
  const float4 k4  = *(const float4*)((base) + 4*NN  + (n0)); \
  const float4 k5  = *(const float4*)((base) + 5*NN  + (n0)); \
  const float4 k6  = *(const float4*)((base) + 6*NN  + (n0)); \
  const float4 k7  = *(const float4*)((base) + 7*NN  + (n0)); \
  const float4 k8  = *(const float4*)((base) + 8*NN  + (n0)); \
  const float4 k9  = *(const float4*)((base) + 9*NN  + (n0)); \
  const float4 k10 = *(const float4*)((base) + 10*NN + (n0)); \
  const float4 k11 = *(const float4*)((base) + 11*NN + (n0)); \
  const float4 k12 = *(const float4*)((base) + 12*NN + (n0)); \
  const float4 k13 = *(const float4*)((base) + 13*NN + (n0)); \
  const float4 k14 = *(const float4*)((base) + 14*NN + (n0)); \
  const float4 k15 = *(const float4*)((base) + 15*NN + (n0));

#define WRED(s) { s += __shfl_xor(s, 32); s += __shfl_xor(s, 16); \
  s += __shfl_xor(s, 8); s += __shfl_xor(s, 4); s += __shfl_xor(s, 2); s += __shfl_xor(s, 1); }

#define LQROW(v, base) \
  const float4 v##0 = *(const float4*)((base)); \
  const float4 v##1 = *(const float4*)((base) + 4); \
  const float4 v##2 = *(const float4*)((base) + 8); \
  const float4 v##3 = *(const float4*)((base) + 12);

// K0: detect input dtype
__global__ __launch_bounds__(256) void k0_detect(
    const unsigned short* __restrict__ ctx_u16, float* __restrict__ flag) {
  const int tid = threadIdx.x;
  int bad = 0;
  for (int i = tid; i < 8192; i += 256) {
    const unsigned short u = ctx_u16[i];
    const int e = (u >> 7) & 0xFF;
    if (e >= 134 || (e >= 1 && e <= 100)) bad++;
  }
  __shared__ int cnt;
  if (tid == 0) cnt = 0;
  __syncthreads();
  atomicAdd(&cnt, bad);
  __syncthreads();
  if (tid == 0) flag[0] = (cnt > 256) ? 1.0f : 0.0f;
}

// K1: q = Wqk @ ctx (row-major + planar), xyz (row + planar), batch sums
__global__ __launch_bounds__(256) void k1_q_xyz(
    const void* __restrict__ ctx, const void* __restrict__ xyz,
    const void* __restrict__ wqk, const float* __restrict__ flag,
    float* __restrict__ qt, float* __restrict__ qk,
    float* __restrict__ xyz4, float* __restrict__ xyzk,
    float* __restrict__ sums) {
  const bool f32 = flag[0] > 0.5f;
  const int tid = threadIdx.x;
  const int b = blockIdx.x >> 4;
  const int n = ((blockIdx.x & 15) << 8) + tid;
  __shared__ float wqT[NQ * NC];  // [c][o]
  for (int i = tid; i < NQ * NC; i += 256) {
    int o = i & 15, c = i >> 4;
    wqT[c * 16 + o] = ldin(wqk, o * 64 + c, f32);
  }
  __syncthreads();
  float4 a0 = {0,0,0,0}, a1 = {0,0,0,0}, a2 = {0,0,0,0}, a3 = {0,0,0,0};
  const size_t cbase = (size_t)b * 64 * NN + n;
#pragma unroll 4
  for (int c = 0; c < 64; ++c) {
    float x = ldin(ctx, cbase + (size_t)c * NN, f32);
    const float4 w0 = *(const float4*)(wqT + c * 16 + 0);
    const float4 w1 = *(const float4*)(wqT + c * 16 + 4);
    const float4 w2 = *(const float4*)(wqT + c * 16 + 8);
    const float4 w3 = *(const float4*)(wqT + c * 16 + 12);
    a0.x = fmaf(w0.x, x, a0.x); a0.y = fmaf(w0.y, x, a0.y); a0.z = fmaf(w0.z, x, a0.z); a0.w = fmaf(w0.w, x, a0.w);
    a1.x = fmaf(w1.x, x, a1.x); a1.y = fmaf(w1.y, x, a1.y); a1.z = fmaf(w1.z, x, a1.z); a1.w = fmaf(w1.w, x, a1.w);
    a2.x = fmaf(w2.x, x, a2.x); a2.y = fmaf(w2.y, x, a2.y); a2.z = fmaf(w2.z, x, a2.z); a2.w = fmaf(w2.w, x, a2.w);
    a3.x = fmaf(w3.x, x, a3.x); a3.y = fmaf(w3.y, x, a3.y); a3.z = fmaf(w3.z, x, a3.z); a3.w = fmaf(w3.w, x, a3.w);
  }
  float* qp = qt + (size_t)(b * NN + n) * 16;
  *(float4*)(qp + 0) = a0; *(float4*)(qp + 4) = a1;
  *(float4*)(qp + 8) = a2; *(float4*)(qp + 12) = a3;
  float* kq = qk + (size_t)b * 16 * NN + n;
  kq[0*NN]=a0.x;  kq[1*NN]=a0.y;  kq[2*NN]=a0.z;  kq[3*NN]=a0.w;
  kq[4*NN]=a1.x;  kq[5*NN]=a1.y;  kq[6*NN]=a1.z;  kq[7*NN]=a1.w;
  kq[8*NN]=a2.x;  kq[9*NN]=a2.y;  kq[10*NN]=a2.z; kq[11*NN]=a2.w;
  kq[12*NN]=a3.x; kq[13*NN]=a3.y; kq[14*NN]=a3.z; kq[15*NN]=a3.w;
  float xx = ldin(xyz, (size_t)(b * NN + n) * 3 + 0, f32);
  float yy = ldin(xyz, (size_t)(b * NN + n) * 3 + 1, f32);
  float zz = ldin(xyz, (size_t)(b * NN + n) * 3 + 2, f32);
  float4 p; p.x = xx; p.y = yy; p.z = zz; p.w = fmaf(xx, xx, fmaf(yy, yy, zz * zz));
  *(float4*)(xyz4 + (size_t)(b * NN + n) * 4) = p;
  float* kx = xyzk + (size_t)b * 4 * NN + n;
  kx[0*NN]=p.x; kx[1*NN]=p.y; kx[2*NN]=p.z; kx[3*NN]=p.w;
  float sx = p.x, sy = p.y, sz = p.z, sw = p.w;
  WRED(sx) WRED(sy) WRED(sz) WRED(sw)
  if ((tid & 63) == 0) {
    atomicAdd(&sums[b * 4 + 0], sx);
    atomicAdd(&sums[b * 4 + 1], sy);
    atomicAdd(&sums[b * 4 + 2], sz);
    atomicAdd(&sums[b * 4 + 3], sw);
  }
}

// K2: xv = Wv @ motion + bv, bf16 channel-major [b][c][n]
__global__ __launch_bounds__(256) void k2_xv(
    const void* __restrict__ mot, const void* __restrict__ wv,
    const void* __restrict__ bv, const float* __restrict__ flag,
    unsigned short* __restrict__ xvb) {
  const bool f32 = flag[0] > 0.5f;
  const int tid = threadIdx.x;
  const int b = blockIdx.x >> 6;
  const int n = ((blockIdx.x & 63) << 6) + (tid >> 2);
  const int og = tid & 3;
  __shared__ float wvT[NC * NC];
  __shared__ float bvs[NC];
  for (int i = tid; i < NC * NC; i += 256) {
    int o = i & 63, c = i >> 6;
    wvT[c * 64 + o] = ldin(wv, o * 64 + c, f32);
  }
  if (tid < 64) bvs[tid] = ldin(bv, tid, f32);
  __syncthreads();
  float4 a0 = *(const float4*)(bvs + og * 16 + 0);
  float4 a1 = *(const float4*)(bvs + og * 16 + 4);
  float4 a2 = *(const float4*)(bvs + og * 16 + 8);
  float4 a3 = *(const float4*)(bvs + og * 16 + 12);
  const size_t mbase = (size_t)b * 64 * NN + n;
#pragma unroll 4
  for (int c = 0; c < 64; ++c) {
    float x = ldin(mot, mbase + (size_t)c * NN, f32);
    const float4 w0 = *(const float4*)(wvT + c * 64 + og * 16 + 0);
    const float4 w1 = *(const float4*)(wvT + c * 64 + og * 16 + 4);
    const float4 w2 = *(const float4*)(wvT + c * 64 + og * 16 + 8);
    const float4 w3 = *(const float4*)(wvT + c * 64 + og * 16 + 12);
    a0.x = fmaf(w0.x, x, a0.x); a0.y = fmaf(w0.y, x, a0.y); a0.z = fmaf(w0.z, x, a0.z); a0.w = fmaf(w0.w, x, a0.w);
    a1.x = fmaf(w1.x, x, a1.x); a1.y = fmaf(w1.y, x, a1.y); a1.z = fmaf(w1.z, x, a1.z); a1.w = fmaf(w1.w, x, a1.w);
    a2.x = fmaf(w2.x, x, a2.x); a2.y = fmaf(w2.y, x, a2.y); a2.z = fmaf(w2.z, x, a2.z); a2.w = fmaf(w2.w, x, a2.w);
    a3.x = fmaf(w3.x, x, a3.x); a3.y = fmaf(w3.y, x, a3.y); a3.z = fmaf(w3.z, x, a3.z); a3.w = fmaf(w3.w, x, a3.w);
  }
  unsigned short* xb = xvb + (size_t)b * 64 * NN + n;
  const int o0 = og * 16;
  xb[(size_t)(o0 + 0) * NN] = f2bf(a0.x);  xb[(size_t)(o0 + 1) * NN] = f2bf(a0.y);
  xb[(size_t)(o0 + 2) * NN] = f2bf(a0.z);  xb[(size_t)(o0 + 3) * NN] = f2bf(a0.w);
  xb[(size_t)(o0 + 4) * NN] = f2bf(a1.x);  xb[(size_t)(o0 + 5) * NN] = f2bf(a1.y);
  xb[(size_t)(o0 + 6) * NN] = f2bf(a1.z);  xb[(size_t)(o0 + 7) * NN] = f2bf(a1.w);
  xb[(size_t)(o0 + 8) * NN] = f2bf(a2.x);  xb[(size_t)(o0 + 9) * NN] = f2bf(a2.y);
  xb[(size_t)(o0 +10) * NN] = f2bf(a2.z);  xb[(size_t)(o0 +11) * NN] = f2bf(a2.w);
  xb[(size_t)(o0 +12) * NN] = f2bf(a3.x);  xb[(size_t)(o0 +13) * NN] = f2bf(a3.y);
  xb[(size_t)(o0 +14) * NN] = f2bf(a3.z);  xb[(size_t)(o0 +15) * NN] = f2bf(a3.w);
}

// K2b: thr[n] = 0.1*(1e-9 + csd[n]) analytic
__global__ __launch_bounds__(256) void k2b_thr(
    const float* __restrict__ xyz4, const float* __restrict__ sums,
    float* __restrict__ thr) {
  const int idx = blockIdx.x * 256 + threadIdx.x;
  const int b = idx >> 12;
  const float4 pn = *(const float4*)(xyz4 + (size_t)idx * 4);
  const float Px = sums[b * 4 + 0], Py = sums[b * 4 + 1];
  const float Pz = sums[b * 4 + 2], S1 = sums[b * 4 + 3];
  float csd = fmaf((float)NN, pn.w, S1)
            - 2.f * (pn.x * Px + pn.y * Py + pn.z * Pz);
  thr[idx] = POS_COEF * (1e-9f + csd);
}

// ===================== fallback (round-13) p1/p3/k7 =====================

__global__ __launch_bounds__(256) void p1_rs1(
    const float* __restrict__ qt, const float* __restrict__ qk,
    float* __restrict__ irs1) {
  const int tid = threadIdx.x;
  const int b = blockIdx.x >> 8;
  const int m0 = (blockIdx.x & 255) << 4;
  const int w = tid >> 6, lane = tid & 63;
  const float* qb = qt + (size_t)b * NN * 16;
  const float* kb = qk + (size_t)b * 16 * NN;
  const int mA = m0 + w, mB = m0 + w + 4, mC = m0 + w + 8, mD = m0 + w + 12;
  LQROW(ma, qb + (size_t)mA * 16)
  LQROW(mb, qb + (size_t)mB * 16)
  LQROW(mc, qb + (size_t)mC * 16)
  LQROW(md, qb + (size_t)mD * 16)
  float sA = 0.f, sB = 0.f, sC = 0.f, sD = 0.f;
  for (int it = 0; it < 16; ++it) {
    const int n0 = (it << 8) + (lane << 2);
    LKPL(kb, n0)
    sA += __expf(fminf(DOTC(ma0,ma1,ma2,ma3,x), 80.f));
    sA += __expf(fminf(DOTC(ma0,ma1,ma2,ma3,y), 80.f));
    sA += __expf(fminf(DOTC(ma0,ma1,ma2,ma3,z), 80.f));
    sA += __expf(fminf(DOTC(ma0,ma1,ma2,ma3,w), 80.f));
    sB += __expf(fminf(DOTC(mb0,mb1,mb2,mb3,x), 80.f));
    sB += __expf(fminf(DOTC(mb0,mb1,mb2,mb3,y), 80.f));
    sB += __expf(fminf(DOTC(mb0,mb1,mb2,mb3,z), 80.f));
    sB += __expf(fminf(DOTC(mb0,mb1,mb2,mb3,w), 80.f));
    sC += __expf(fminf(DOTC(mc0,mc1,mc2,mc3,x), 80.f));
    sC += __expf(fminf(DOTC(mc0,mc1,mc2,mc3,y), 80.f));
    sC += __expf(fminf(DOTC(mc0,mc1,mc2,mc3,z), 80.f));
    sC += __expf(fminf(DOTC(mc0,mc1,mc2,mc3,w), 80.f));
    sD += __expf(fminf(DOTC(md0,md1,md2,md3,x), 80.f));
    sD += __expf(fminf(DOTC(md0,md1,md2,md3,y), 80.f));
    sD += __expf(fminf(DOTC(md0,md1,md2,md3,z), 80.f));
    sD += __expf(fminf(DOTC(md0,md1,md2,md3,w), 80.f));
  }
  WRED(sA) WRED(sB) WRED(sC) WRED(sD)
  if (lane == 0) {
    irs1[b * NN + mA] = rcpf_(sA);
    irs1[b * NN + mB] = rcpf_(sB);
    irs1[b * NN + mC] = rcpf_(sC);
    irs1[b * NN + mD] = rcpf_(sD);
  }
}

__global__ __launch_bounds__(256) void p3_rs2(
    const float* __restrict__ qt, const float* __restrict__ qk,
    const float* __restrict__ xyz4, const float* __restrict__ xyzk,
    const float* __restrict__ irs1, const float* __restrict__ ics1,
    const float* __restrict__ thr, float* __restrict__ irs2) {
  const int tid = threadIdx.x;
  const int b = blockIdx.x >> 8;
  const int m0 = (blockIdx.x & 255) << 4;
  const int w = tid >> 6, lane = tid & 63;
  const float* qb = qt + (size_t)b * NN * 16;
  const float* kb = qk + (size_t)b * 16 * NN;
  const float* xk = xyzk + (size_t)b * 4 * NN;
  const int mA = m0 + w, mB = m0 + w + 4, mC = m0 + w + 8, mD = m0 + w + 12;
  LQROW(ma, qb + (size_t)mA * 16)
  LQROW(mb, qb + (size_t)mB * 16)
  LQROW(mc, qb + (size_t)mC * 16)
  LQROW(md, qb + (size_t)mD * 16)
  const float4 pmA = *(const float4*)(xyz4 + ((size_t)b * NN + mA) * 4);
  const float4 pmB = *(const float4*)(xyz4 + ((size_t)b * NN + mB) * 4);
  const float4 pmC = *(const float4*)(xyz4 + ((size_t)b * NN + mC) * 4);
  const float4 pmD = *(const float4*)(xyz4 + ((size_t)b * NN + mD) * 4);
  const float rA = irs1[b * NN + mA];
  const float rB = irs1[b * NN + mB];
  const float rC = irs1[b * NN + mC];
  const float rD = irs1[b * NN + mD];
  float sA = 0.f, sB = 0.f, sC = 0.f, sD = 0.f;
#define P3C(S, M0,M1,M2,M3, PM, R, C) { \
    float corr_ = DOTC(M0,M1,M2,M3,C); \
    float a1v_ = __expf(fminf(corr_, 80.f)) * (R) * ic.C; \
    float dd_ = (PM).w + pw.C - 2.f * ((PM).x * px.C + (PM).y * py.C + (PM).z * pz.C); \
    dd_ = fmaxf(dd_, 0.f); \
    float l0_ = (dd_ <= th.C) ? a1v_ : 0.f; \
    S += __expf(l0_); }
  for (int it = 0; it < 16; ++it) {
    const int n0 = (it << 8) + (lane << 2);
    LKPL(kb, n0)
    const float4 px = *(const float4*)(xk + 0*NN + n0);
    const float4 py = *(const float4*)(xk + 1*NN + n0);
    const float4 pz = *(const float4*)(xk + 2*NN + n0);
    const float4 pw = *(const float4*)(xk + 3*NN + n0);
    const float4 ic = *(const float4*)(ics1 + b * NN + n0);
    const float4 th = *(const float4*)(thr + b * NN + n0);
    P3C(sA, ma0,ma1,ma2,ma3, pmA, rA, x)
    P3C(sA, ma0,ma1,ma2,ma3, pmA, rA, y)
    P3C(sA, ma0,ma1,ma2,ma3, pmA, rA, z)
    P3C(sA, ma0,ma1,ma2,ma3, pmA, rA, w)
    P3C(sB, mb0,mb1,mb2,mb3, pmB, rB, x)
    P3C(sB, mb0,mb1,mb2,mb3, pmB, rB, y)
    P3C(sB, mb0,mb1,mb2,mb3, pmB, rB, z)
    P3C(sB, mb0,mb1,mb2,mb3, pmB, rB, w)
    P3C(sC, mc0,mc1,mc2,mc3, pmC, rC, x)
    P3C(sC, mc0,mc1,mc2,mc3, pmC, rC, y)
    P3C(sC, mc0,mc1,mc2,mc3, pmC, rC, z)
    P3C(sC, mc0,mc1,mc2,mc3, pmC, rC, w)
    P3C(sD, md0,md1,md2,md3, pmD, rD, x)
    P3C(sD, md0,md1,md2,md3, pmD, rD, y)
    P3C(sD, md0,md1,md2,md3, pmD, rD, z)
    P3C(sD, md0,md1,md2,md3, pmD, rD, w)
  }
#undef P3C
  WRED(sA) WRED(sB) WRED(sC) WRED(sD)
  if (lane == 0) {
    irs2[b * NN + mA] = rcpf_(sA);
    irs2[b * NN + mB] = rcpf_(sB);
    irs2[b * NN + mC] = rcpf_(sC);
    irs2[b * NN + mD] = rcpf_(sD);
  }
}

__global__ __launch_bounds__(256) void k7_gma(
    const float* __restrict__ qt, const float* __restrict__ xyz4,
    const unsigned short* __restrict__ xvb,
    const float* __restrict__ irs1, const float* __restrict__ irs2,
    const float* __restrict__ ics1, const float* __restrict__ thr,
    float* __restrict__ g1, float* __restrict__ g2, float* __restrict__ cs2) {
  const int tid = threadIdx.x;
  const int bid = blockIdx.x;
  const int msl = bid & 7;
  const int nb = (bid >> 3) & 63;
  const int b = bid >> 9;
  const int n0 = nb << 6;
  const int mstart = msl << 9;
  __shared__ __align__(16) unsigned short attns1[64 * 72];
  __shared__ __align__(16) unsigned short attns2[64 * 72];
  __shared__ __align__(16) unsigned short xvs[64 * 72];
  const float* qb = qt + (size_t)b * NN * 16;
  const float* pb = xyz4 + (size_t)b * NN * 4;
  const int ni = tid & 63, aw = tid >> 6;
  const int na = n0 + ni;
  const float* qnp = qb + (size_t)na * 16;
  LQROW(q, qnp)
  const float4 pn = *(const float4*)(pb + (size_t)na * 4);
  const float ics1n = ics1[b * NN + na];
  const float thr_n = thr[b * NN + na];
  const int lane = tid & 63, wv = tid >> 6;
  const int lr = lane & 15, quad = lane >> 4;
  const int nw = wv << 4;
  f32x4v acc0 = {0,0,0,0}, acc1 = {0,0,0,0}, acc2 = {0,0,0,0}, acc3 = {0,0,0,0};
  f32x4v d0 = {0,0,0,0}, d1 = {0,0,0,0}, d2 = {0,0,0,0}, d3 = {0,0,0,0};
  float csacc = 0.f;
#define COMPA(MOFF, D1, D2) { \
    const int m_ = __builtin_amdgcn_readfirstlane(mw + (MOFF)); \
    const float* qm_ = qb + (size_t)m_ * 16; \
    LQROW(wq, qm_) \
    float corr_ = DOT16M(q0, q1, q2, q3, wq0, wq1, wq2, wq3); \
    const float4 pm_ = *(const float4*)(pb + (size_t)m_ * 4); \
    float a1v_ = __expf(fminf(corr_, 80.f)) * irs1[b * NN + m_] * ics1n; \
    float dd_ = pm_.w + pn.w - 2.f * (pm_.x * pn.x + pm_.y * pn.y + pm_.z * pn.z); \
    dd_ = fmaxf(dd_, 0.f); \
    float l0_ = (dd_ <= thr_n) ? a1v_ : 0.f; \
    float l2n_ = __expf(l0_) * irs2[b * NN + m_]; \
    D1 = f2bf(a1v_); D2 = f2bf(l2n_); csacc += l2n_; }
  for (int mt = 0; mt < 8; ++mt) {
    const int m0 = mstart + (mt << 6);
    __syncthreads();
    {
      const int c = tid >> 2, part = tid & 3;
      const unsigned short* src = xvb + ((size_t)b * 64 + c) * NN + m0 + part * 16;
      unsigned short* dst = xvs + c * 72 + part * 16;
      *(uint4*)dst = *(const uint4*)src;
      *(uint4*)(dst + 8) = *(const uint4*)(src + 8);
    }
    const int mw = m0 + (aw << 4);
#pragma unroll
    for (int g = 0; g < 4; ++g) {
      ushort4 u1, u2;
      COMPA(g * 4 + 0, u1.x, u2.x)
      COMPA(g * 4 + 1, u1.y, u2.y)
      COMPA(g * 4 + 2, u1.z, u2.z)
      COMPA(g * 4 + 3, u1.w, u2.w)
      *(ushort4*)(attns1 + ni * 72 + (aw << 4) + (g << 2)) = u1;
      *(ushort4*)(attns2 + ni * 72 + (aw << 4) + (g << 2)) = u2;
    }
    __syncthreads();
#pragma unroll
    for (int h = 0; h < 2; ++h) {
      const bf16x8 a1 = *(const bf16x8*)(attns1 + (nw + lr) * 72 + h * 32 + quad * 8);
      const bf16x8 a2 = *(const bf16x8*)(attns2 + (nw + lr) * 72 + h * 32 + quad * 8);
      const bf16x8 b0 = *(const bf16x8*)(xvs + (lr) * 72 + h * 32 + quad * 8);
      const bf16x8 b1 = *(const bf16x8*)(xvs + (16 + lr) * 72 + h * 32 + quad * 8);
      const bf16x8 b2 = *(const bf16x8*)(xvs + (32 + lr) * 72 + h * 32 + quad * 8);
      const bf16x8 b3 = *(const bf16x8*)(xvs + (48 + lr) * 72 + h * 32 + quad * 8);
      acc0 = __builtin_amdgcn_mfma_f32_16x16x32_bf16(a1, b0, acc0, 0, 0, 0);
      acc1 = __builtin_amdgcn_mfma_f32_16x16x32_bf16(a1, b1, acc1, 0, 0, 0);
      acc2 = __builtin_amdgcn_mfma_f32_16x16x32_bf16(a1, b2, acc2, 0, 0, 0);
      acc3 = __builtin_amdgcn_mfma_f32_16x16x32_bf16(a1, b3, acc3, 0, 0, 0);
      d0 = __builtin_amdgcn_mfma_f32_16x16x32_bf16(a2, b0, d0, 0, 0, 0);
      d1 = __builtin_amdgcn_mfma_f32_16x16x32_bf16(a2, b1, d1, 0, 0, 0);
      d2 = __builtin_amdgcn_mfma_f32_16x16x32_bf16(a2, b2, d2, 0, 0, 0);
      d3 = __builtin_amdgcn_mfma_f32_16x16x32_bf16(a2, b3, d3, 0, 0, 0);
    }
  }
#undef COMPA
  atomicAdd(&cs2[b * NN + na], csacc);
#define EPI(ACC, DST, CT) { \
    float* g_ = (DST) + ((size_t)b * NN + n0 + nw + (quad << 2)) * 64 + (CT) * 16 + lr; \
    atomicAdd(g_ + 0,   ACC[0]); \
    atomicAdd(g_ + 64,  ACC[1]); \
    atomicAdd(g_ + 128, ACC[2]); \
    atomicAdd(g_ + 192, ACC[3]); }
  EPI(acc0, g1, 0) EPI(acc1, g1, 1) EPI(acc2, g1, 2) EPI(acc3, g1, 3)
  EPI(d0, g2, 0) EPI(d1, g2, 1) EPI(d2, g2, 2) EPI(d3, g2, 3)
#undef EPI
}

// ============ materialized-exp path (used iff ws_size permits) ============

// P1W: stores a0[m][n]=bf16(exp(corr)), sums ROUNDED values.
// 1024 blocks (8-row strips, 2 rows/wave) for occupancy: was 512-block /
// 2-block-per-CU -> latency-bound at 40% VALUBusy.
__global__ __launch_bounds__(256) void p1w_rs1(
    const float* __restrict__ qt, const float* __restrict__ qk,
    float* __restrict__ irs1, unsigned short* __restrict__ a0g) {
  const int tid = threadIdx.x;
  const int b = blockIdx.x >> 9;
  const int m0 = (blockIdx.x & 511) << 3;
  const int w = tid >> 6, lane = tid & 63;
  const float* qb = qt + (size_t)b * NN * 16;
  const float* kb = qk + (size_t)b * 16 * NN;
  unsigned short* ab = a0g + (size_t)b * NN * NN;
  const int mA = m0 + w, mB = m0 + w + 4;
  LQROW(ma, qb + (size_t)mA * 16)
  LQROW(mb, qb + (size_t)mB * 16)
  float sA = 0.f, sB = 0.f;
#define P1E(S, U, UC, M0,M1,M2,M3, C) { \
    float e_ = __expf(fminf(DOTC(M0,M1,M2,M3,C), 80.f)); \
    unsigned short us_ = f2bf(e_); U.UC = us_; S += bf2f(us_); }
  for (int it = 0; it < 16; ++it) {
    const int n0 = (it << 8) + (lane << 2);
    LKPL(kb, n0)
    ushort4 uA, uB;
    P1E(sA, uA, x, ma0,ma1,ma2,ma3, x) P1E(sA, uA, y, ma0,ma1,ma2,ma3, y)
    P1E(sA, uA, z, ma0,ma1,ma2,ma3, z) P1E(sA, uA, w, ma0,ma1,ma2,ma3, w)
    P1E(sB, uB, x, mb0,mb1,mb2,mb3, x) P1E(sB, uB, y, mb0,mb1,mb2,mb3, y)
    P1E(sB, uB, z, mb0,mb1,mb2,mb3, z) P1E(sB, uB, w, mb0,mb1,mb2,mb3, w)
    *(ushort4*)(ab + (size_t)mA * NN + n0) = uA;
    *(ushort4*)(ab + (size_t)mB * NN + n0) = uB;
  }
#undef P1E
  WRED(sA) WRED(sB)
  if (lane == 0) {
    irs1[b * NN + mA] = rcpf_(sA);
    irs1[b * NN + mB] = rcpf_(sB);
  }
}

// P2R: cs1 via SYMMETRY of corr: cs1[n] = sum_m a0[n][m]*irs1[m].
__global__ __launch_bounds__(256) void p2r_cs1(
    const unsigned short* __restrict__ a0g, const float* __restrict__ irs1,
    float* __restrict__ ics1) {
  const int tid = threadIdx.x;
  const int w = tid >> 6, l = tid & 63;
  const int bi = blockIdx.x;                 // 0..2047
  const int b = bi >> 10;
  const int n = ((bi & 1023) << 2) + w;      // 4 rows per block, 1 per wave
  const unsigned short* row = a0g + ((size_t)b * NN + n) * NN;
  const float* ir = irs1 + b * NN;
  float s = 0.f;
#pragma unroll
  for (int it = 0; it < 8; ++it) {
    const int m = (it << 9) + (l << 3);
    const uint4 u = *(const uint4*)(row + m);
    const float4 i0 = *(const float4*)(ir + m);
    const float4 i1 = *(const float4*)(ir + m + 4);
    s = fmaf(bf2f((unsigned short)(u.x & 0xffffu)), i0.x, s);
    s = fmaf(bf2f((unsigned short)(u.x >> 16)),     i0.y, s);
    s = fmaf(bf2f((unsigned short)(u.y & 0xffffu)), i0.z, s);
    s = fmaf(bf2f((unsigned short)(u.y >> 16)),     i0.w, s);
    s = fmaf(bf2f((unsigned short)(u.z & 0xffffu)), i1.x, s);
    s = fmaf(bf2f((unsigned short)(u.z >> 16)),     i1.y, s);
    s = fmaf(bf2f((unsigned short)(u.w & 0xffffu)), i1.z, s);
    s = fmaf(bf2f((unsigned short)(u.w >> 16)),     i1.w, s);
  }
  WRED(s)
  if (l == 0) ics1[b * NN + n] = rcpf_(1e-9f + s);
}

// P3W: reads a0 rows, stores ae[m][n]=bf16(exp(l0)), sums ROUNDED values.
// 1024 blocks (8-row strips, 2 rows/wave) -- occupancy fix, same numerics.
__global__ __launch_bounds__(256) void p3w_rs2(
    const float* __restrict__ xyz4, const float* __restrict__ xyzk,
    const float* __restrict__ irs1, const float* __restrict__ ics1,
    const float* __restrict__ thr, float* __restrict__ irs2,
    const unsigned short* __restrict__ a0g, unsigned short* __restrict__ aeg) {
  const int tid = threadIdx.x;
  const int b = blockIdx.x >> 9;
  const int m0 = (blockIdx.x & 511) << 3;
  const int w = tid >> 6, lane = tid & 63;
  const float* xk = xyzk + (size_t)b * 4 * NN;
  const unsigned short* ab = a0g + (size_t)b * NN * NN;
  unsigned short* eb = aeg + (size_t)b * NN * NN;
  const int mA = m0 + w, mB = m0 + w + 4;
  const float4 pmA = *(const float4*)(xyz4 + ((size_t)b * NN + mA) * 4);
  const float4 pmB = *(const float4*)(xyz4 + ((size_t)b * NN + mB) * 4);
  const float rA = irs1[b * NN + mA];
  const float rB = irs1[b * NN + mB];
  float sA = 0.f, sB = 0.f;
#define P3W(S, RU, EU, UC, PM, R, C) { \
    float a1v_ = bf2f(RU.UC) * (R) * ic.C; \
    float dd_ = (PM).w + pw.C - 2.f * ((PM).x * px.C + (PM).y * py.C + (PM).z * pz.C); \
    dd_ = fmaxf(dd_, 0.f); \
    float l0_ = (dd_ <= th.C) ? a1v_ : 0.f; \
    unsigned short us_ = f2bf(__expf(l0_)); EU.UC = us_; S += bf2f(us_); }
  for (int it = 0; it < 16; ++it) {
    const int n0 = (it << 8) + (lane << 2);
    const float4 px = *(const float4*)(xk + 0*NN + n0);
    const float4 py = *(const float4*)(xk + 1*NN + n0);
    const float4 pz = *(const float4*)(xk + 2*NN + n0);
    const float4 pw = *(const float4*)(xk + 3*NN + n0);
    const float4 ic = *(const float4*)(ics1 + b * NN + n0);
    const float4 th = *(const float4*)(thr + b * NN + n0);
    const ushort4 rA4 = *(const ushort4*)(ab + (size_t)mA * NN + n0);
    const ushort4 rB4 = *(const ushort4*)(ab + (size_t)mB * NN + n0);
    ushort4 eA, eB;
    P3W(sA, rA4, eA, x, pmA, rA, x) P3W(sA, rA4, eA, y, pmA, rA, y)
    P3W(sA, rA4, eA, z, pmA, rA, z) P3W(sA, rA4, eA, w, pmA, rA, w)
    P3W(sB, rB4, eB, x, pmB, rB, x) P3W(sB, rB4, eB, y, pmB, rB, y)
    P3W(sB, rB4, eB, z, pmB, rB, z) P3W(sB, rB4, eB, w, pmB, rB, w)
    *(ushort4*)(eb + (size_t)mA * NN + n0) = eA;
    *(ushort4*)(eb + (size_t)mB * NN + n0) = eB;
  }
#undef P3W
  WRED(sA) WRED(sB)
  if (lane == 0) {
    irs2[b * NN + mA] = rcpf_(sA);
    irs2[b * NN + mB] = rcpf_(sB);
  }
}

// P4: cs2[n] = sum_m bf16(bf16(ae[m][n]) * irs2[m]) -- exact match of what
// k7n stages into the MFMA.  1024 blocks (64-row m strips) -- occupancy fix.
__global__ __launch_bounds__(256) void p4_cs2(
    const unsigned short* __restrict__ aeg, const float* __restrict__ irs2,
    float* __restrict__ cs2) {
  const int tid = threadIdx.x;
  const int bid = blockIdx.x;              // B*8*64 = 1024 blocks
  const int ms = bid & 63;                 // m strip (64 rows)
  const int ng = (bid >> 6) & 7;           // n group (512 cols)
  const int b  = bid >> 9;
  const int n2 = (ng << 9) + (tid << 1);   // 2 columns per thread
  const unsigned short* eb = aeg + (size_t)b * NN * NN + n2;
  const float* r2 = irs2 + b * NN;
  float s0 = 0.f, s1 = 0.f;
  const int m0 = ms << 6;
#pragma unroll 4
  for (int m = m0; m < m0 + 64; ++m) {
    const unsigned u = *(const unsigned*)(eb + (size_t)m * NN);
    const float r = r2[m];
    s0 += bf2f(f2bf(bf2f((unsigned short)(u & 0xffffu)) * r));
    s1 += bf2f(f2bf(bf2f((unsigned short)(u >> 16)) * r));
  }
  atomicAdd(&cs2[b * NN + n2], s0);
  atomicAdd(&cs2[b * NN + n2 + 1], s1);
}

// LDS swizzle: spreads both the b32 transpose-writes (2-way, free) and the
// b128 reads (uniform) across banks.
#define SW(r) ((((r) & 7) << 4) ^ ((((r) >> 3) & 3) << 5))

// K7N: GMA with fused g1/g2 combine (needs cs2 from p4).
__global__ __launch_bounds__(256) void k7n_gma(
    const unsigned short* __restrict__ a0g, const unsigned short* __restrict__ aeg,
    const unsigned short* __restrict__ xvb,
    const float* __restrict__ irs1, const float* __restrict__ irs2,
    const float* __restrict__ ics1, const float* __restrict__ cs2,
    float* __restrict__ gma) {
  const int tid = threadIdx.x;
  const int bid = blockIdx.x;              // 512 blocks: B * 64 nb * 4 msl
  const int msl = bid & 3;
  const int nb  = (bid >> 2) & 63;
  const int b   = bid >> 8;
  const int n0 = nb << 6;
  const int mstart = msl << 10;            // 1024-row m strip -> 16 tiles
  __shared__ __align__(16) unsigned short attns1[2][64 * 64];
  __shared__ __align__(16) unsigned short attns2[2][64 * 64];
  __shared__ __align__(16) unsigned short xvs[2][64 * 64];
  const unsigned short* ab = a0g + (size_t)b * NN * NN;
  const unsigned short* ebp = aeg + (size_t)b * NN * NN;
  const float* irs1b = irs1 + b * NN;
  const float* irs2b = irs2 + b * NN;
  const int w = tid >> 6, l = tid & 63;
  const int lrow0 = (w << 4) + ((l >> 3) << 1);
  const int nc8 = (l & 7) << 3;
  const int gcol = n0 + nc8;
  const int xc = tid >> 2, xpart = tid & 3;
  const unsigned short* xvp = xvb + ((size_t)b * 64 + xc) * NN;
  const int lr = l & 15, quad = l >> 4;
  const int nw = w << 4;
  f32x4v acc0 = {0,0,0,0}, acc1 = {0,0,0,0}, acc2 = {0,0,0,0}, acc3 = {0,0,0,0};
  f32x4v d0 = {0,0,0,0}, d1 = {0,0,0,0}, d2 = {0,0,0,0}, d3 = {0,0,0,0};

  uint4 pa0A, pa1A, pe0A, pe1A, pv0A, pv1A;
  uint4 pa0B, pa1B, pe0B, pe1B, pv0B, pv1B;
  float r1aA, r1bA, r2aA, r2bA, r1aB, r1bB, r2aB, r2bB;

#define ISSUE(S, MT) { \
    const int m0_ = mstart + ((MT) << 6); \
    const size_t ra_ = (size_t)(m0_ + lrow0) * NN + gcol; \
    pa0##S = *(const uint4*)(ab + ra_); \
    pa1##S = *(const uint4*)(ab + ra_ + NN); \
    pe0##S = *(const uint4*)(ebp + ra_); \
    pe1##S = *(const uint4*)(ebp + ra_ + NN); \
    pv0##S = *(const uint4*)(xvp + m0_ + (xpart << 4)); \
    pv1##S = *(const uint4*)(xvp + m0_ + (xpart << 4) + 8); \
    r1a##S = irs1b[m0_ + lrow0]; r1b##S = irs1b[m0_ + lrow0 + 1]; \
    r2a##S = irs2b[m0_ + lrow0]; r2b##S = irs2b[m0_ + lrow0 + 1]; }

#define CVW(D0, D1, SH, J, R0, R1, ARR) { \
    const float v0_ = bf2f((unsigned short)(((D0) >> (SH)) & 0xffffu)) * (R0); \
    const float v1_ = bf2f((unsigned short)(((D1) >> (SH)) & 0xffffu)) * (R1); \
    const unsigned pk_ = (unsigned)f2bf(v0_) | ((unsigned)f2bf(v1_) << 16); \
    const int nl_ = nc8 + (J); \
    *(unsigned*)((char*)(ARR) + ((((nl_) << 7) + (lrow0 << 1)) ^ SW(nl_))) = pk_; }

#define WR8(U0, U1, R0, R1, ARR) \
    CVW(U0.x, U1.x, 0,  0, R0, R1, ARR) CVW(U0.x, U1.x, 16, 1, R0, R1, ARR) \
    CVW(U0.y, U1.y, 0,  2, R0, R1, ARR) CVW(U0.y, U1.y, 16, 3, R0, R1, ARR) \
    CVW(U0.z, U1.z, 0,  4, R0, R1, ARR) CVW(U0.z, U1.z, 16, 5, R0, R1, ARR) \
    CVW(U0.w, U1.w, 0,  6, R0, R1, ARR) CVW(U0.w, U1.w, 16, 7, R0, R1, ARR)

#define STX(XARR, PV0, PV1) { \
    const int xb_ = (xc << 7) + (xpart << 5); \
    *(uint4*)((char*)(XARR) + ((xb_) ^ SW(xc))) = PV0; \
    *(uint4*)((char*)(XARR) + ((xb_ + 16) ^ SW(xc))) = PV1; }

#define LDSW(ARR, ROW, H, Q) \
    (*(const bf16x8*)((const char*)(ARR) + \
      ((((ROW) << 7) + ((H) << 6) + ((Q) << 4)) ^ SW(ROW))))

#define MPH(A1P, A2P, XVP_) { \
    for (int h = 0; h < 2; ++h) { \
      const bf16x8 fa1 = LDSW(A1P, nw + lr, h, quad); \
      const bf16x8 fa2 = LDSW(A2P, nw + lr, h, quad); \
      const bf16x8 fb0 = LDSW(XVP_, lr, h, quad); \
      const bf16x8 fb1 = LDSW(XVP_, 16 + lr, h, quad); \
      const bf16x8 fb2 = LDSW(XVP_, 32 + lr, h, quad); \
      const bf16x8 fb3 = LDSW(XVP_, 48 + lr, h, quad); \
      acc0 = __builtin_amdgcn_mfma_f32_16x16x32_bf16(fa1, fb0, acc0, 0, 0, 0); \
      acc1 = __builtin_amdgcn_mfma_f32_16x16x32_bf16(fa1, fb1, acc1, 0, 0, 0); \
      acc2 = __builtin_amdgcn_mfma_f32_16x16x32_bf16(fa1, fb2, acc2, 0, 0, 0); \
      acc3 = __builtin_amdgcn_mfma_f32_16x16x32_bf16(fa1, fb3, acc3, 0, 0, 0); \
      d0 = __builtin_amdgcn_mfma_f32_16x16x32_bf16(fa2, fb0, d0, 0, 0, 0); \
      d1 = __builtin_amdgcn_mfma_f32_16x16x32_bf16(fa2, fb1, d1, 0, 0, 0); \
      d2 = __builtin_amdgcn_mfma_f32_16x16x32_bf16(fa2, fb2, d2, 0, 0, 0); \
      d3 = __builtin_amdgcn_mfma_f32_16x16x32_bf16(fa2, fb3, d3, 0, 0, 0); \
    } }

  ISSUE(A, 0)
  ISSUE(B, 1)
  for (int mt = 0; mt < 16; mt += 2) {
    WR8(pa0A, pa1A, r1aA, r1bA, attns1[0])
    WR8(pe0A, pe1A, r2aA, r2bA, attns2[0])
    STX(xvs[0], pv0A, pv1A)
    __syncthreads();
    if (mt + 2 < 16) { ISSUE(A, mt + 2) }
    MPH(attns1[0], attns2[0], xvs[0])
    WR8(pa0B, pa1B, r1aB, r1bB, attns1[1])
    WR8(pe0B, pe1B, r2aB, r2bB, attns2[1])
    STX(xvs[1], pv0B, pv1B)
    __syncthreads();
    if (mt + 3 < 16) { ISSUE(B, mt + 3) }
    MPH(attns1[1], attns2[1], xvs[1])
  }
#undef ISSUE
#undef CVW
#undef WR8
#undef STX
#undef LDSW
#undef MPH
  float w10, w11, w12, w13, w20, w21, w22, w23;
  {
    const int nr = n0 + nw + (quad << 2);
    w10 = ics1[b * NN + nr + 0]; w20 = rcpf_(1e-9f + cs2[b * NN + nr + 0]);
    w11 = ics1[b * NN + nr + 1]; w21 = rcpf_(1e-9f + cs2[b * NN + nr + 1]);
    w12 = ics1[b * NN + nr + 2]; w22 = rcpf_(1e-9f + cs2[b * NN + nr + 2]);
    w13 = ics1[b * NN + nr + 3]; w23 = rcpf_(1e-9f + cs2[b * NN + nr + 3]);
  }
#define EPI(ACC, DD, CT) { \
    float* g_ = gma + ((size_t)b * NN + n0 + nw + (quad << 2)) * 64 + (CT) * 16 + lr; \
    atomicAdd(g_ + 0,   fmaf(ACC[0], w10, DD[0] * w20)); \
    atomicAdd(g_ + 64,  fmaf(ACC[1], w11, DD[1] * w21)); \
    atomicAdd(g_ + 128, fmaf(ACC[2], w12, DD[2] * w22)); \
    atomicAdd(g_ + 192, fmaf(ACC[3], w13, DD[3] * w23)); }
  EPI(acc0, d0, 0) EPI(acc1, d1, 1) EPI(acc2, d2, 2) EPI(acc3, d3, 3)
#undef EPI
}

// ===================== common p2 / k8 / k9 =====================

__global__ __launch_bounds__(256) void p2_cs1(
    const float* __restrict__ qt, const float* __restrict__ qk,
    const float* __restrict__ irs1, float* __restrict__ ics1) {
  const int tid = threadIdx.x;
  const int b = blockIdx.x >> 8;
  const int n0t = (blockIdx.x & 255) << 4;
  const int w = tid >> 6, lane = tid & 63;
  const float* qb = qt + (size_t)b * NN * 16;
  const float* kb = qk + (size_t)b * 16 * NN;
  const int nA = n0t + w, nB = n0t + w + 4, nC = n0t + w + 8, nD = n0t + w + 12;
  LQROW(na, qb + (size_t)nA * 16)
  LQROW(nb, qb + (size_t)nB * 16)
  LQROW(nc, qb + (size_t)nC * 16)
  LQROW(nd, qb + (size_t)nD * 16)
  float sA = 0.f, sB = 0.f, sC = 0.f, sD = 0.f;
  for (int it = 0; it < 16; ++it) {
    const int m0 = (it << 8) + (lane << 2);
    LKPL(kb, m0)
    const float4 r1 = *(const float4*)(irs1 + b * NN + m0);
    sA = fmaf(__expf(fminf(DOTC(na0,na1,na2,na3,x), 80.f)), r1.x, sA);
    sA = fmaf(__expf(fminf(DOTC(na0,na1,na2,na3,y), 80.f)), r1.y, sA);
    sA = fmaf(__expf(fminf(DOTC(na0,na1,na2,na3,z), 80.f)), r1.z, sA);
    sA = fmaf(__expf(fminf(DOTC(na0,na1,na2,na3,w), 80.f)), r1.w, sA);
    sB = fmaf(__expf(fminf(DOTC(nb0,nb1,nb2,nb3,x), 80.f)), r1.x, sB);
    sB = fmaf(__expf(fminf(DOTC(nb0,nb1,nb2,nb3,y), 80.f)), r1.y, sB);
    sB = fmaf(__expf(fminf(DOTC(nb0,nb1,nb2,nb3,z), 80.f)), r1.z, sB);
    sB = fmaf(__expf(fminf(DOTC(nb0,nb1,nb2,nb3,w), 80.f)), r1.w, sB);
    sC = fmaf(__expf(fminf(DOTC(nc0,nc1,nc2,nc3,x), 80.f)), r1.x, sC);
    sC = fmaf(__expf(fminf(DOTC(nc0,nc1,nc2,nc3,y), 80.f)), r1.y, sC);
    sC = fmaf(__expf(fminf(DOTC(nc0,nc1,nc2,nc3,z), 80.f)), r1.z, sC);
    sC = fmaf(__expf(fminf(DOTC(nc0,nc1,nc2,nc3,w), 80.f)), r1.w, sC);
    sD = fmaf(__expf(fminf(DOTC(nd0,nd1,nd2,nd3,x), 80.f)), r1.x, sD);
    sD = fmaf(__expf(fminf(DOTC(nd0,nd1,nd2,nd3,y), 80.f)), r1.y, sD);
    sD = fmaf(__expf(fminf(DOTC(nd0,nd1,nd2,nd3,z), 80.f)), r1.z, sD);
    sD = fmaf(__expf(fminf(DOTC(nd0,nd1,nd2,nd3,w), 80.f)), r1.w, sD);
  }
  WRED(sA) WRED(sB) WRED(sC) WRED(sD)
  if (lane == 0) {
    ics1[b * NN + nA] = rcpf_(1e-9f + sA);
    ics1[b * NN + nB] = rcpf_(1e-9f + sB);
    ics1[b * NN + nC] = rcpf_(1e-9f + sC);
    ics1[b * NN + nD] = rcpf_(1e-9f + sD);
  }
}

// mode 0: gma = g1 + g2*ics2 (fallback);  mode 2: gma already combined in g1.
__global__ __launch_bounds__(256) void k8_res(
    const void* __restrict__ mot, const void* __restrict__ wt,
    const void* __restrict__ bt, const float* __restrict__ flag,
    float* __restrict__ g1_res, const float* __restrict__ g2,
    const float* __restrict__ cs2, float* __restrict__ gn,
    const float* __restrict__ ics1, int g1mode) {
  const bool f32 = flag[0] > 0.5f;
  const int tid = threadIdx.x;
  const int bid = blockIdx.x;
  const int b = bid >> 9;
  const int n0 = (bid & 511) << 3;
  __shared__ float wtT[64 * 65];
  __shared__ float bts[64];
  __shared__ float md[8 * 64];
  __shared__ float gs[8], gss[8];
  for (int i = tid; i < 4096; i += 256) {
    int o = i & 63, c = i >> 6;
    wtT[c * 65 + o] = ldin(wt, o * 64 + c, f32);
  }
  if (tid < 64) bts[tid] = ldin(bt, tid, f32);
  if (tid < 8) { gs[tid] = 0.f; gss[tid] = 0.f; }
#pragma unroll
  for (int r = 0; r < 2; ++r) {
    const int idx = tid * 2 + r;
    const int c = idx & 63, nl = idx >> 6;
    const size_t gi = ((size_t)b * NN + n0 + nl) * 64 + c;
    float gmav;
    if (g1mode == 2) {
      gmav = g1_res[gi];
    } else {
      const float ics2n = rcpf_(1e-9f + cs2[b * NN + n0 + nl]);
      float g1v = g1_res[gi];
      if (g1mode == 1) g1v *= ics1[b * NN + n0 + nl];
      gmav = fmaf(g2[gi], ics2n, g1v);
    }
    md[nl * 64 + c] = ldin(mot, ((size_t)b * 64 + c) * NN + n0 + nl, f32) - gmav;
  }
  __syncthreads();
  const int o = tid & 63, ng = tid >> 6;
  const int nl0 = ng * 2, nl1 = ng * 2 + 1;
  float a0 = bts[o], a1 = bts[o];
#pragma unroll 8
  for (int c = 0; c < 64; ++c) {
    float w = wtT[c * 65 + o];
    a0 = fmaf(w, md[nl0 * 64 + c], a0);
    a1 = fmaf(w, md[nl1 * 64 + c], a1);
  }
  g1_res[((size_t)b * NN + n0 + nl0) * 64 + o] = a0;
  g1_res[((size_t)b * NN + n0 + nl1) * 64 + o] = a1;
  atomicAdd(&gs[o >> 3], a0 + a1);
  atomicAdd(&gss[o >> 3], a0 * a0 + a1 * a1);
  __syncthreads();
  if (tid < 8) atomicAdd(&gn[b * 8 + tid], gs[tid]);
  else if (tid < 16) atomicAdd(&gn[16 + b * 8 + (tid - 8)], gss[tid - 8]);
}

__global__ __launch_bounds__(256) void k9_out(
    const float* __restrict__ res, const float* __restrict__ gn,
    const void* __restrict__ mot,
    const void* __restrict__ gnw, const void* __restrict__ gnb,
    const void* __restrict__ pa, const void* __restrict__ al,
    const float* __restrict__ flag, void* __restrict__ out) {
  const bool f32 = flag[0] > 0.5f;
  const int idx = blockIdx.x * 256 + threadIdx.x;
  const int n = idx & 4095;
  const int c = (idx >> 12) & 63;
  const int b = idx >> 18;
  const int g = c >> 3;
  const float inv_cnt = 1.f / 32768.f;
  float mean = gn[b * 8 + g] * inv_cnt;
  float var = gn[16 + b * 8 + g] * inv_cnt - mean * mean;
  var = fmaxf(var, 0.f);
  float rstd = rsqrtf(var + 1e-5f);
  float r = res[((size_t)b * NN + n) * 64 + c];
  float y = (r - mean) * rstd * ldin(gnw, c, f32) + ldin(gnb, c, f32);
  float slope = ldin(pa, 0, f32);
  y = (y >= 0.f) ? y : slope * y;
  float o = ldin(al, 0, f32) * y + ldin(mot, idx, f32);
  if (f32) ((float*)out)[idx] = o;
  else     ((__hip_bfloat16*)out)[idx] = __float2bfloat16(o);
}

extern "C" void kernel_launch(void* const* d_in, const int* in_sizes, int n_in,
                              void* d_out, int out_size, void* d_ws, size_t ws_size,
                              hipStream_t stream) {
  const void* ctx = d_in[0];
  const void* mot = d_in[1];
  const void* xyz = d_in[2];
  const void* wqk = d_in[3];
  const void* wv  = d_in[4];
  const void* bv  = d_in[5];
  const void* wt  = d_in[6];
  const void* bt  = d_in[7];
  const void* gnw = d_in[8];
  const void* gnb = d_in[9];
  const void* pa  = d_in[10];
  const void* al  = d_in[11];
  float* ws = (float*)d_ws;
  const bool big = ws_size >= (size_t)FULL_F * sizeof(float);

  if (ws_size < (size_t)WS_TOTAL * sizeof(float))
    fprintf(stderr, "[gma3d] WARNING ws_size=%zu < needed %zu\n",
            ws_size, (size_t)WS_TOTAL * sizeof(float));

  hipMemsetAsync(ws + OFF_SUMS, 0, (size_t)ZERO_F * sizeof(float), stream);

  k0_detect<<<1, 256, 0, stream>>>((const unsigned short*)ctx, ws + OFF_FLAG);
  k1_q_xyz<<<32, 256, 0, stream>>>(ctx, xyz, wqk, ws + OFF_FLAG,
                                   ws + OFF_QT, ws + OFF_QK,
                                   ws + OFF_XYZ4, ws + OFF_XYZK, ws + OFF_SUMS);
  k2_xv<<<128, 256, 0, stream>>>(mot, wv, bv, ws + OFF_FLAG,
                                 (unsigned short*)(ws + OFF_XVB));
  k2b_thr<<<32, 256, 0, stream>>>(ws + OFF_XYZ4, ws + OFF_SUMS, ws + OFF_THR);

  if (big) {
    unsigned short* a0 = (unsigned short*)(ws + OFF_A0);
    unsigned short* ae = (unsigned short*)(ws + OFF_AE);
    p1w_rs1<<<1024, 256, 0, stream>>>(ws + OFF_QT, ws + OFF_QK, ws + OFF_IRS1, a0);
    p2r_cs1<<<2048, 256, 0, stream>>>(a0, ws + OFF_IRS1, ws + OFF_ICS1);
    p3w_rs2<<<1024, 256, 0, stream>>>(ws + OFF_XYZ4, ws + OFF_XYZK,
                                      ws + OFF_IRS1, ws + OFF_ICS1, ws + OFF_THR,
                                      ws + OFF_IRS2, a0, ae);
    p4_cs2<<<1024, 256, 0, stream>>>(ae, ws + OFF_IRS2, ws + OFF_CS2);
    k7n_gma<<<512, 256, 0, stream>>>(a0, ae,
                                     (const unsigned short*)(ws + OFF_XVB),
                                     ws + OFF_IRS1, ws + OFF_IRS2,
                                     ws + OFF_ICS1, ws + OFF_CS2,
                                     ws + OFF_GMA);
    k8_res<<<1024, 256, 0, stream>>>(mot, wt, bt, ws + OFF_FLAG,
                                     ws + OFF_GMA, ws + OFF_G2, ws + OFF_CS2,
                                     ws + OFF_GN, ws + OFF_ICS1, 2);
  } else {
    p1_rs1<<<512, 256, 0, stream>>>(ws + OFF_QT, ws + OFF_QK, ws + OFF_IRS1);
    p2_cs1<<<512, 256, 0, stream>>>(ws + OFF_QT, ws + OFF_QK, ws + OFF_IRS1, ws + OFF_ICS1);
    p3_rs2<<<512, 256, 0, stream>>>(ws + OFF_QT, ws + OFF_QK,
                                    ws + OFF_XYZ4, ws + OFF_XYZK,
                                    ws + OFF_IRS1, ws + OFF_ICS1, ws + OFF_THR,
                                    ws + OFF_IRS2);
    k7_gma<<<1024, 256, 0, stream>>>(ws + OFF_QT, ws + OFF_XYZ4,
                                     (const unsigned short*)(ws + OFF_XVB),
                                     ws + OFF_IRS1, ws + OFF_IRS2,
                                     ws + OFF_ICS1, ws + OFF_THR,
                                     ws + OFF_GMA, ws + OFF_G2, ws + OFF_CS2);
    k8_res<<<1024, 256, 0, stream>>>(mot, wt, bt, ws + OFF_FLAG,
                                     ws + OFF_GMA, ws + OFF_G2, ws + OFF_CS2,
                                     ws + OFF_GN, ws + OFF_ICS1, 0);
  }

  k9_out<<<2048, 256, 0, stream>>>(ws + OFF_GMA, ws + OFF_GN, mot, gnw, gnb, pa, al,
                                   ws + OFF_FLAG, d_out);
}